// Round 8
// baseline (479.079 us; speedup 1.0000x reference)
//
#include <hip/hip_runtime.h>
#include <hip/hip_fp16.h>
#include <cstdint>

#define HIDDEN 1024
#define ATTN   512
#define NB     8
#define SEQ    2048
#define MROWS  (NB*SEQ)   // 16384

typedef _Float16 f16x8 __attribute__((ext_vector_type(8)));
typedef float    f32x4 __attribute__((ext_vector_type(4)));

__device__ __forceinline__ float tanh_fast(float x){
  float e = __expf(2.0f*x);
  return 1.0f - 2.0f/(e + 1.0f);
}

__device__ __forceinline__ void gload16(const void* g, void* l){
  __builtin_amdgcn_global_load_lds((const __attribute__((address_space(1))) void*)g,
                                   (__attribute__((address_space(3))) void*)l, 16, 0, 0);
}

// ---------------- K0a: cast inputs f32 -> fp16 ----------------
__global__ __launch_bounds__(256) void k_cast_x(const float* __restrict__ x, __half* __restrict__ xh){
  size_t i = (size_t)blockIdx.x*256 + threadIdx.x;
  const float4* src = reinterpret_cast<const float4*>(x) + i*2;
  float4 a = src[0], b = src[1];
  f16x8 h;
  h[0]=(_Float16)a.x; h[1]=(_Float16)a.y; h[2]=(_Float16)a.z; h[3]=(_Float16)a.w;
  h[4]=(_Float16)b.x; h[5]=(_Float16)b.y; h[6]=(_Float16)b.z; h[7]=(_Float16)b.w;
  reinterpret_cast<f16x8*>(xh)[i] = h;
}

// ---------------- K0b: W[1024][512] f32 -> WhT[512][1024] fp16 (x3) ----------------
__global__ __launch_bounds__(256) void k_transpose_w(const float* __restrict__ Wq, const float* __restrict__ Wk,
                                                     const float* __restrict__ Wv, __half* __restrict__ whT){
  __shared__ float lds[32][33];
  int which = blockIdx.y;
  const float* W = which==0 ? Wq : (which==1 ? Wk : Wv);
  int tr = blockIdx.x >> 4;
  int tc = blockIdx.x & 15;
  int t = threadIdx.x;
  {
    int r = t >> 3, c4 = (t & 7)*4;
    float4 v = *reinterpret_cast<const float4*>(W + (size_t)(tr*32 + r)*ATTN + tc*32 + c4);
    lds[r][c4+0]=v.x; lds[r][c4+1]=v.y; lds[r][c4+2]=v.z; lds[r][c4+3]=v.w;
  }
  __syncthreads();
  {
    int n = t >> 3, k4 = (t & 7)*4;
    ushort4 u;
    u.x = __half_as_ushort(__float2half(lds[k4+0][n]));
    u.y = __half_as_ushort(__float2half(lds[k4+1][n]));
    u.z = __half_as_ushort(__float2half(lds[k4+2][n]));
    u.w = __half_as_ushort(__float2half(lds[k4+3][n]));
    *reinterpret_cast<ushort4*>(whT + (size_t)which*ATTN*HIDDEN + (size_t)(tc*32 + n)*HIDDEN + tr*32 + k4) = u;
  }
}

// ---------------- K1: fused QKV projection, q/k/v = tanh(x@W + b), fp16 out ----------------
__global__ __launch_bounds__(256,3) void k_proj(const __half* __restrict__ xh, const __half* __restrict__ whT,
                                                const float* __restrict__ bq, const float* __restrict__ bk,
                                                const float* __restrict__ bv,
                                                __half* __restrict__ qh, __half* __restrict__ kh, __half* __restrict__ vh){
  __shared__ __align__(16) _Float16 lA[128*64];   // 16 KB
  __shared__ __align__(16) _Float16 lB[128*64];   // 16 KB
  int nt = blockIdx.x;             // 0..11 : which = nt>>2, 128-col slab = nt&3
  int m0 = blockIdx.y * 128;
  int which = nt >> 2;
  int ncol0 = (nt & 3) * 128;
  int t = threadIdx.x;
  int w = t >> 6, lane = t & 63;
  int lrow = lane & 15, lk = lane >> 4;
  int wm = w >> 1, wn = w & 1;

  int rr = lane >> 3;
  int ss = (lane & 7) ^ rr;
  const __half* Abase = xh + (size_t)(m0 + w*32 + rr)*HIDDEN + ss*8;
  const __half* Bbase = whT + (size_t)which*ATTN*HIDDEN + (size_t)(ncol0 + w*32 + rr)*HIDDEN + ss*8;
  _Float16* lAw = &lA[(w*32)*64];
  _Float16* lBw = &lB[(w*32)*64];

  f32x4 acc[4][4];
  #pragma unroll
  for (int i=0;i<4;i++)
    #pragma unroll
    for (int j=0;j<4;j++) acc[i][j] = f32x4{0.f,0.f,0.f,0.f};

  for (int k0 = 0; k0 < HIDDEN; k0 += 64){
    __syncthreads();
    #pragma unroll
    for (int c=0; c<4; c++){
      gload16(Abase + (size_t)c*8*HIDDEN + k0, &lAw[c*8*64]);
      gload16(Bbase + (size_t)c*8*HIDDEN + k0, &lBw[c*8*64]);
    }
    __syncthreads();
    #pragma unroll
    for (int u=0; u<2; u++){
      f16x8 af[4], bf[4];
      #pragma unroll
      for (int fm=0; fm<4; fm++){
        int row = wm*64 + fm*16 + lrow;
        af[fm] = *(const f16x8*)&lA[row*64 + (((u*4 + lk) ^ (row & 7))*8)];
      }
      #pragma unroll
      for (int fn=0; fn<4; fn++){
        int row = wn*64 + fn*16 + lrow;
        bf[fn] = *(const f16x8*)&lB[row*64 + (((u*4 + lk) ^ (row & 7))*8)];
      }
      #pragma unroll
      for (int fm=0; fm<4; fm++)
        #pragma unroll
        for (int fn=0; fn<4; fn++)
          acc[fm][fn] = __builtin_amdgcn_mfma_f32_16x16x32_f16(af[fm], bf[fn], acc[fm][fn], 0,0,0);
    }
  }

  const float* bias = which==0 ? bq : (which==1 ? bk : bv);
  __half* dst = which==0 ? qh : (which==1 ? kh : vh);
  #pragma unroll
  for (int fn=0; fn<4; fn++){
    int col = ncol0 + wn*64 + fn*16 + lrow;
    float bb = bias[col];
    #pragma unroll
    for (int fm=0; fm<4; fm++)
      #pragma unroll
      for (int mi=0; mi<4; mi++){
        int row = m0 + wm*64 + fm*16 + lk*4 + mi;
        dst[(size_t)row*ATTN + col] = __float2half(tanh_fast(acc[fm][fn][mi] + bb));
      }
  }
}

// ---------------- K1b: vh[16384][512] -> vT[8][512][2048] (per-batch transpose) ----------------
__global__ __launch_bounds__(256) void k_transpose_v(const __half* __restrict__ vh, __half* __restrict__ vT){
  __shared__ _Float16 lds[64][80];
  int r0 = blockIdx.x * 64;
  int c0 = blockIdx.y * 64;
  int b = r0 / SEQ, j0 = r0 % SEQ;
  int t = threadIdx.x;
  #pragma unroll
  for (int it=0; it<2; it++){
    int g = it*256 + t;
    int r = g >> 3, s = g & 7;
    f16x8 v = *(const f16x8*)(vh + (size_t)(r0 + r)*ATTN + c0 + s*8);
    #pragma unroll
    for (int i=0;i<8;i++) lds[s*8+i][r] = v[i];
  }
  __syncthreads();
  #pragma unroll
  for (int it=0; it<2; it++){
    int g = it*256 + t;
    int ar = g >> 3, s = g & 7;
    f16x8 v = *(const f16x8*)&lds[ar][s*8];
    *(f16x8*)(vT + ((size_t)b*ATTN + c0 + ar)*SEQ + j0 + s*8) = v;
  }
}

// ---------------- K2: scores + no-max softmax -> probs, software-pipelined ----------------
// Swapped-operand S^T = mfma(K,Q). Next iteration's 8 kf loads issue BEFORE the MFMA
// cluster (one-iteration load-to-use distance hides L2 latency). launch_bounds(1024,2)
// lifts reg cap to 256 (kf+kn ~64 VGPR live + 64 AGPR acc).
__global__ __launch_bounds__(1024,2) void k_scores(const __half* __restrict__ qh, const __half* __restrict__ kh,
                                                   float* __restrict__ probs){
  __shared__ float red[16][32];
  int bid = blockIdx.x;
  int b  = bid & 7;            // XCD pin: batch's kh slice (2 MB) resident in one XCD L2
  int i0 = (bid >> 3) * 32;
  int t = threadIdx.x;
  int w = t >> 6, lane = t & 63;
  int lrow = lane & 15, lk = lane >> 4;
  size_t qrow0 = (size_t)b*SEQ + i0;
  size_t krow0 = (size_t)b*SEQ + w*128;

  f32x4 acc[2][8];
  #pragma unroll
  for (int i=0;i<2;i++)
    #pragma unroll
    for (int j=0;j<8;j++) acc[i][j] = f32x4{0.f,0.f,0.f,0.f};

  const __half* kbase = kh + (krow0 + lrow)*ATTN + lk*8;   // +fn*16*ATTN per frag
  const __half* qbase = qh + (qrow0 + lrow)*ATTN + lk*8;

  f16x8 kf[8];
  #pragma unroll
  for (int fn=0; fn<8; fn++) kf[fn] = *(const f16x8*)(kbase + (size_t)fn*16*ATTN);

  #pragma unroll 2
  for (int it=0; it<16; it++){
    int k0 = it*32;
    f16x8 aq0 = *(const f16x8*)(qbase + k0);
    f16x8 aq1 = *(const f16x8*)(qbase + (size_t)16*ATTN + k0);
    f16x8 kn[8];
    if (it < 15){
      #pragma unroll
      for (int fn=0; fn<8; fn++)
        kn[fn] = *(const f16x8*)(kbase + (size_t)fn*16*ATTN + k0 + 32);
    }
    #pragma unroll
    for (int fn=0; fn<8; fn++){
      acc[0][fn] = __builtin_amdgcn_mfma_f32_16x16x32_f16(kf[fn], aq0, acc[0][fn], 0,0,0);
      acc[1][fn] = __builtin_amdgcn_mfma_f32_16x16x32_f16(kf[fn], aq1, acc[1][fn], 0,0,0);
    }
    #pragma unroll
    for (int fn=0; fn<8; fn++) kf[fn] = kn[fn];
  }

  // no-max softmax: |s*scale| <= 22.63, f32-safe (verified round 7)
  const float scale = 0.044194173824159216f;   // 1/sqrt(512)
  float sm[2];
  #pragma unroll
  for (int nf=0;nf<2;nf++){
    float s = 0.f;
    #pragma unroll
    for (int fn=0;fn<8;fn++)
      #pragma unroll
      for (int mi=0;mi<4;mi++){
        float e = __expf(acc[nf][fn][mi] * scale);
        acc[nf][fn][mi] = e;
        s += e;
      }
    s += __shfl_xor(s, 16);
    s += __shfl_xor(s, 32);
    sm[nf] = s;
  }
  if (lane < 16){ red[w][lane] = sm[0]; red[w][16 + lane] = sm[1]; }
  __syncthreads();
  float inv[2];
  #pragma unroll
  for (int nf=0;nf<2;nf++){
    float tot = 0.f;
    #pragma unroll
    for (int ww=0; ww<16; ww++) tot += red[ww][nf*16 + lrow];
    inv[nf] = 1.0f / tot;
  }
  float* dst = probs + (size_t)b*SEQ*SEQ;
  #pragma unroll
  for (int nf=0;nf<2;nf++){
    size_t rowoff = (size_t)(i0 + nf*16 + lrow)*SEQ + w*128 + lk*4;
    f32x4 iv = {inv[nf], inv[nf], inv[nf], inv[nf]};
    #pragma unroll
    for (int fn=0;fn<8;fn++){
      f32x4 v = acc[nf][fn] * iv;
      __builtin_nontemporal_store(v, (f32x4*)(dst + rowoff + fn*16));
    }
  }
}

// ---------------- K3: context = probs @ v, software-pipelined bv prefetch ----------------
// 64x512 tile, 256 blocks = 1/CU, 8 waves. bvA/bvB register double-buffer: each u-half's
// 8 vT loads issue one half-iteration ahead of their MFMAs.
__global__ __launch_bounds__(512,2) void k_pv(const float* __restrict__ probs, const __half* __restrict__ vT,
                                              float* __restrict__ out0){
  __shared__ __align__(16) _Float16 lA[64*64];   // 8 KB
  int bid = blockIdx.x;
  int b  = bid & 7;            // XCD pin: vT[b] L2-resident
  int i0 = (bid >> 3) * 64;
  int t = threadIdx.x;
  int w = t >> 6, lane = t & 63;
  int lrow = lane & 15, lk = lane >> 4;
  int wm = w >> 2, wn = w & 3;
  int sr = t >> 3, ssc = t & 7;

  const float*  psrc  = probs + ((size_t)b*SEQ + i0 + sr)*SEQ + ssc*8;
  const __half* vbase = vT + (size_t)b*ATTN*SEQ + (size_t)(wn*128 + lrow)*SEQ + lk*8;  // +fn*16*SEQ
  int dst_sl = (ssc ^ (sr & 7)) * 8;

  f32x4 acc[2][8];
  #pragma unroll
  for (int i=0;i<2;i++)
    #pragma unroll
    for (int j=0;j<8;j++) acc[i][j] = f32x4{0.f,0.f,0.f,0.f};

  float4 p0 = *(const float4*)(psrc);
  float4 p1 = *(const float4*)(psrc + 4);

  f16x8 bvA[8], bvB[8];
  #pragma unroll
  for (int fn=0; fn<8; fn++) bvA[fn] = *(const f16x8*)(vbase + (size_t)fn*16*SEQ);   // k0=0, u=0

  for (int k0 = 0; k0 < SEQ; k0 += 64){
    f16x8 hv;
    hv[0]=(_Float16)p0.x; hv[1]=(_Float16)p0.y; hv[2]=(_Float16)p0.z; hv[3]=(_Float16)p0.w;
    hv[4]=(_Float16)p1.x; hv[5]=(_Float16)p1.y; hv[6]=(_Float16)p1.z; hv[7]=(_Float16)p1.w;
    __syncthreads();
    *(f16x8*)&lA[sr*64 + dst_sl] = hv;
    __syncthreads();
    if (k0 + 64 < SEQ){
      p0 = *(const float4*)(psrc + k0 + 64);
      p1 = *(const float4*)(psrc + k0 + 68);
    }
    // u=0: issue u=1 loads, compute with bvA
    #pragma unroll
    for (int fn=0; fn<8; fn++) bvB[fn] = *(const f16x8*)(vbase + (size_t)fn*16*SEQ + k0 + 32);
    {
      f16x8 af[2];
      #pragma unroll
      for (int fm=0; fm<2; fm++){
        int row = wm*32 + fm*16 + lrow;
        af[fm] = *(const f16x8*)&lA[row*64 + ((lk ^ (row & 7))*8)];
      }
      #pragma unroll
      for (int fn=0; fn<8; fn++){
        acc[0][fn] = __builtin_amdgcn_mfma_f32_16x16x32_f16(af[0], bvA[fn], acc[0][fn], 0,0,0);
        acc[1][fn] = __builtin_amdgcn_mfma_f32_16x16x32_f16(af[1], bvA[fn], acc[1][fn], 0,0,0);
      }
    }
    // u=1: issue next-k0 u=0 loads, compute with bvB
    if (k0 + 64 < SEQ){
      #pragma unroll
      for (int fn=0; fn<8; fn++) bvA[fn] = *(const f16x8*)(vbase + (size_t)fn*16*SEQ + k0 + 64);
    }
    {
      f16x8 af[2];
      #pragma unroll
      for (int fm=0; fm<2; fm++){
        int row = wm*32 + fm*16 + lrow;
        af[fm] = *(const f16x8*)&lA[row*64 + (((4 + lk) ^ (row & 7))*8)];
      }
      #pragma unroll
      for (int fn=0; fn<8; fn++){
        acc[0][fn] = __builtin_amdgcn_mfma_f32_16x16x32_f16(af[0], bvB[fn], acc[0][fn], 0,0,0);
        acc[1][fn] = __builtin_amdgcn_mfma_f32_16x16x32_f16(af[1], bvB[fn], acc[1][fn], 0,0,0);
      }
    }
  }

  float* dst = out0 + ((size_t)b*SEQ + i0)*ATTN;
  #pragma unroll
  for (int fm=0; fm<2; fm++)
    #pragma unroll
    for (int fn=0; fn<8; fn++)
      #pragma unroll
      for (int mi=0; mi<4; mi++)
        dst[(size_t)(wm*32 + fm*16 + lk*4 + mi)*ATTN + wn*128 + fn*16 + lrow] = tanh_fast(acc[fm][fn][mi]);
}

extern "C" void kernel_launch(void* const* d_in, const int* in_sizes, int n_in,
                              void* d_out, int out_size, void* d_ws, size_t ws_size,
                              hipStream_t stream){
  const float* x  = (const float*)d_in[0];
  const float* Wq = (const float*)d_in[1];
  const float* bq = (const float*)d_in[2];
  const float* Wk = (const float*)d_in[3];
  const float* bk = (const float*)d_in[4];
  const float* Wv = (const float*)d_in[5];
  const float* bv = (const float*)d_in[6];

  float* out0 = (float*)d_out;                        // [8,2048,512]  tanh(context)   33.55 MB
  float* out1 = out0 + (size_t)NB*SEQ*ATTN;           // [8,2048,2048] probs          134.2 MB

  const size_t SZ = 16777216;                         // 16.78 MB
  char* ws = (char*)d_ws;
  // out1 region (written only by k_scores): xh | whT | vh overlay
  __half* xh  = (__half*)out1;
  __half* whT = (__half*)((char*)out1 + 2*SZ);
  __half* vh  = (__half*)((char*)out1 + 2*SZ + 3145728);
  __half* vT  = (__half*)ws;

  if (ws_size >= 3*SZ){
    // qh/kh in d_ws (round 7 confirmed ws_size >= 50.3 MB)
    __half* qh = (__half*)(ws + SZ);
    __half* kh = (__half*)(ws + 2*SZ);
    k_cast_x     <<<8192,        256, 0, stream>>>(x, xh);
    k_transpose_w<<<dim3(512,3), 256, 0, stream>>>(Wq, Wk, Wv, whT);
    k_proj       <<<dim3(12,128),256, 0, stream>>>(xh, whT, bq, bk, bv, qh, kh, vh);
    k_transpose_v<<<dim3(256,8), 256, 0, stream>>>(vh, vT);
    k_scores     <<<512,        1024, 0, stream>>>(qh, kh, out1);
    k_pv         <<<256,         512, 0, stream>>>(out1, vT, out0);
  } else {
    // fallback: qh/kh overlay out0 (safe: out0 written only by k_pv, after qh/kh dead)
    __half* qh = (__half*)out0;
    __half* kh = (__half*)out0 + (size_t)MROWS*ATTN;
    k_cast_x     <<<8192,        256, 0, stream>>>(x, xh);
    k_transpose_w<<<dim3(512,3), 256, 0, stream>>>(Wq, Wk, Wv, whT);
    k_proj       <<<dim3(12,128),256, 0, stream>>>(xh, whT, bq, bk, bv, qh, kh, vh);
    k_transpose_v<<<dim3(256,8), 256, 0, stream>>>(vh, vT);
    k_scores     <<<512,        1024, 0, stream>>>(qh, kh, out1);
    k_pv         <<<256,         512, 0, stream>>>(out1, vT, out0);
  }
}

// Round 9
// 391.943 us; speedup vs baseline: 1.2223x; 1.2223x over previous
//
#include <hip/hip_runtime.h>
#include <hip/hip_fp16.h>
#include <cstdint>

#define HIDDEN 1024
#define ATTN   512
#define NB     8
#define SEQ    2048
#define MROWS  (NB*SEQ)   // 16384

typedef _Float16 f16x8 __attribute__((ext_vector_type(8)));
typedef float    f32x4 __attribute__((ext_vector_type(4)));

// Fragment-major tiled layout for MFMA operands:
//   addr(r, a) = (r>>4)*8192 + (a>>5)*512 + (r&15)*32 + (a&31)     [halfs]
// A wave's 16x32 fragment (lane l: row l&15, dims (l>>4)*8..+8) is one contiguous
// 1KB block => single-segment global load instead of 16 scattered 128B segments.

__device__ __forceinline__ float tanh_fast(float x){
  float e = __expf(2.0f*x);
  return 1.0f - 2.0f/(e + 1.0f);
}

__device__ __forceinline__ void gload16(const void* g, void* l){
  __builtin_amdgcn_global_load_lds((const __attribute__((address_space(1))) void*)g,
                                   (__attribute__((address_space(3))) void*)l, 16, 0, 0);
}

// ---------------- K0a: cast inputs f32 -> fp16 ----------------
__global__ __launch_bounds__(256) void k_cast_x(const float* __restrict__ x, __half* __restrict__ xh){
  size_t i = (size_t)blockIdx.x*256 + threadIdx.x;
  const float4* src = reinterpret_cast<const float4*>(x) + i*2;
  float4 a = src[0], b = src[1];
  f16x8 h;
  h[0]=(_Float16)a.x; h[1]=(_Float16)a.y; h[2]=(_Float16)a.z; h[3]=(_Float16)a.w;
  h[4]=(_Float16)b.x; h[5]=(_Float16)b.y; h[6]=(_Float16)b.z; h[7]=(_Float16)b.w;
  reinterpret_cast<f16x8*>(xh)[i] = h;
}

// ---------------- K0b: W[1024][512] f32 -> WhT[512][1024] fp16 (x3) ----------------
__global__ __launch_bounds__(256) void k_transpose_w(const float* __restrict__ Wq, const float* __restrict__ Wk,
                                                     const float* __restrict__ Wv, __half* __restrict__ whT){
  __shared__ float lds[32][33];
  int which = blockIdx.y;
  const float* W = which==0 ? Wq : (which==1 ? Wk : Wv);
  int tr = blockIdx.x >> 4;
  int tc = blockIdx.x & 15;
  int t = threadIdx.x;
  {
    int r = t >> 3, c4 = (t & 7)*4;
    float4 v = *reinterpret_cast<const float4*>(W + (size_t)(tr*32 + r)*ATTN + tc*32 + c4);
    lds[r][c4+0]=v.x; lds[r][c4+1]=v.y; lds[r][c4+2]=v.z; lds[r][c4+3]=v.w;
  }
  __syncthreads();
  {
    int n = t >> 3, k4 = (t & 7)*4;
    ushort4 u;
    u.x = __half_as_ushort(__float2half(lds[k4+0][n]));
    u.y = __half_as_ushort(__float2half(lds[k4+1][n]));
    u.z = __half_as_ushort(__float2half(lds[k4+2][n]));
    u.w = __half_as_ushort(__float2half(lds[k4+3][n]));
    *reinterpret_cast<ushort4*>(whT + (size_t)which*ATTN*HIDDEN + (size_t)(tc*32 + n)*HIDDEN + tr*32 + k4) = u;
  }
}

// ---------------- K1: fused QKV projection ----------------
// q/k outputs in fragment-tiled layout; v stays row-major (repacked by k_transpose_v).
__global__ __launch_bounds__(256,3) void k_proj(const __half* __restrict__ xh, const __half* __restrict__ whT,
                                                const float* __restrict__ bq, const float* __restrict__ bk,
                                                const float* __restrict__ bv,
                                                __half* __restrict__ qh, __half* __restrict__ kh, __half* __restrict__ vh){
  __shared__ __align__(16) _Float16 lA[128*64];   // 16 KB
  __shared__ __align__(16) _Float16 lB[128*64];   // 16 KB
  int nt = blockIdx.x;             // 0..11 : which = nt>>2, 128-col slab = nt&3
  int m0 = blockIdx.y * 128;
  int which = nt >> 2;
  int ncol0 = (nt & 3) * 128;
  int t = threadIdx.x;
  int w = t >> 6, lane = t & 63;
  int lrow = lane & 15, lk = lane >> 4;
  int wm = w >> 1, wn = w & 1;

  int rr = lane >> 3;
  int ss = (lane & 7) ^ rr;
  const __half* Abase = xh + (size_t)(m0 + w*32 + rr)*HIDDEN + ss*8;
  const __half* Bbase = whT + (size_t)which*ATTN*HIDDEN + (size_t)(ncol0 + w*32 + rr)*HIDDEN + ss*8;
  _Float16* lAw = &lA[(w*32)*64];
  _Float16* lBw = &lB[(w*32)*64];

  f32x4 acc[4][4];
  #pragma unroll
  for (int i=0;i<4;i++)
    #pragma unroll
    for (int j=0;j<4;j++) acc[i][j] = f32x4{0.f,0.f,0.f,0.f};

  for (int k0 = 0; k0 < HIDDEN; k0 += 64){
    __syncthreads();
    #pragma unroll
    for (int c=0; c<4; c++){
      gload16(Abase + (size_t)c*8*HIDDEN + k0, &lAw[c*8*64]);
      gload16(Bbase + (size_t)c*8*HIDDEN + k0, &lBw[c*8*64]);
    }
    __syncthreads();
    #pragma unroll
    for (int u=0; u<2; u++){
      f16x8 af[4], bf[4];
      #pragma unroll
      for (int fm=0; fm<4; fm++){
        int row = wm*64 + fm*16 + lrow;
        af[fm] = *(const f16x8*)&lA[row*64 + (((u*4 + lk) ^ (row & 7))*8)];
      }
      #pragma unroll
      for (int fn=0; fn<4; fn++){
        int row = wn*64 + fn*16 + lrow;
        bf[fn] = *(const f16x8*)&lB[row*64 + (((u*4 + lk) ^ (row & 7))*8)];
      }
      #pragma unroll
      for (int fm=0; fm<4; fm++)
        #pragma unroll
        for (int fn=0; fn<4; fn++)
          acc[fm][fn] = __builtin_amdgcn_mfma_f32_16x16x32_f16(af[fm], bf[fn], acc[fm][fn], 0,0,0);
    }
  }

  const float* bias = which==0 ? bq : (which==1 ? bk : bv);
  __half* dst = which==0 ? qh : (which==1 ? kh : vh);
  if (which < 2){
    // fragment-tiled store: (r>>4)*8192 + (a>>5)*512 + (r&15)*32 + (a&31)
    int rt_base = (m0 >> 4) + wm*4;          // + fm
    int at_base = (ncol0 >> 5) + wn*2;       // + (fn>>1)
    #pragma unroll
    for (int fn=0; fn<4; fn++){
      int col = ncol0 + wn*64 + fn*16 + lrow;
      float bb = bias[col];
      int at = at_base + (fn >> 1);
      int asub = (fn & 1)*16 + lrow;
      #pragma unroll
      for (int fm=0; fm<4; fm++){
        size_t tbase = (size_t)(rt_base + fm)*8192 + (size_t)at*512 + asub;
        #pragma unroll
        for (int mi=0; mi<4; mi++)
          dst[tbase + (lk*4 + mi)*32] = __float2half(tanh_fast(acc[fm][fn][mi] + bb));
      }
    }
  } else {
    #pragma unroll
    for (int fn=0; fn<4; fn++){
      int col = ncol0 + wn*64 + fn*16 + lrow;
      float bb = bias[col];
      #pragma unroll
      for (int fm=0; fm<4; fm++)
        #pragma unroll
        for (int mi=0; mi<4; mi++){
          int row = m0 + wm*64 + fm*16 + lk*4 + mi;
          dst[(size_t)row*ATTN + col] = __float2half(tanh_fast(acc[fm][fn][mi] + bb));
        }
    }
  }
}

// ---------------- K1b: vh[16384][512] -> vT tiled [8][512/16][2048/32][16][32] ----------------
__global__ __launch_bounds__(256) void k_transpose_v(const __half* __restrict__ vh, __half* __restrict__ vT){
  __shared__ _Float16 lds[64][80];
  int r0 = blockIdx.x * 64;          // key rows
  int c0 = blockIdx.y * 64;          // attn cols
  int b = r0 / SEQ, j0 = r0 % SEQ;
  int t = threadIdx.x;
  #pragma unroll
  for (int it=0; it<2; it++){
    int g = it*256 + t;
    int r = g >> 3, s = g & 7;
    f16x8 v = *(const f16x8*)(vh + (size_t)(r0 + r)*ATTN + c0 + s*8);
    #pragma unroll
    for (int i=0;i<8;i++) lds[s*8+i][r] = v[i];
  }
  __syncthreads();
  __half* vb = vT + (size_t)b*ATTN*SEQ;
  #pragma unroll
  for (int it=0; it<2; it++){
    int g = it*256 + t;
    int ar = g >> 3, s = g & 7;     // ar: attn row in tile (0..63), s: key-octet (0..7)
    f16x8 v = *(const f16x8*)&lds[ar][s*8];
    int a = c0 + ar;
    int j = j0 + s*8;
    // tiled: (a>>4)*(16*SEQ) + (j>>5)*512 + (a&15)*32 + (j&31)
    *(f16x8*)(vb + (size_t)(a >> 4)*(16*SEQ) + (size_t)(j >> 5)*512 + (a & 15)*32 + (j & 31)) = v;
  }
}

// ---------------- K2: scores + no-max softmax -> probs (fragment-tiled loads) ----------------
// Round-5 structure (proven no-spill); every kf/aq load is one contiguous 1KB segment.
__global__ __launch_bounds__(1024,4) void k_scores(const __half* __restrict__ qh, const __half* __restrict__ kh,
                                                   float* __restrict__ probs){
  __shared__ float red[16][32];
  int bid = blockIdx.x;
  int b  = bid & 7;            // XCD pin: batch's kh slice (2 MB) resident in one XCD L2
  int i0 = (bid >> 3) * 32;
  int t = threadIdx.x;
  int w = t >> 6, lane = t & 63;
  int lrow = lane & 15, lk = lane >> 4;
  int loff = lrow*32 + lk*8;

  const __half* kbase = kh + (size_t)((b*SEQ + w*128) >> 4)*8192 + loff;  // +fn*8192 + it*512
  const __half* qbase = qh + (size_t)((b*SEQ + i0) >> 4)*8192 + loff;     // +nf*8192 + it*512

  f32x4 acc[2][8];
  #pragma unroll
  for (int i=0;i<2;i++)
    #pragma unroll
    for (int j=0;j<8;j++) acc[i][j] = f32x4{0.f,0.f,0.f,0.f};

  for (int it = 0; it < 16; it++){
    f16x8 aq0 = *(const f16x8*)(qbase + it*512);
    f16x8 aq1 = *(const f16x8*)(qbase + 8192 + it*512);
    #pragma unroll
    for (int fn=0; fn<8; fn++){
      f16x8 kf = *(const f16x8*)(kbase + (size_t)fn*8192 + it*512);
      acc[0][fn] = __builtin_amdgcn_mfma_f32_16x16x32_f16(kf, aq0, acc[0][fn], 0,0,0);
      acc[1][fn] = __builtin_amdgcn_mfma_f32_16x16x32_f16(kf, aq1, acc[1][fn], 0,0,0);
    }
  }

  // no-max softmax: |s*scale| <= 22.63, f32-safe (verified rounds 7-8)
  const float scale = 0.044194173824159216f;   // 1/sqrt(512)
  float sm[2];
  #pragma unroll
  for (int nf=0;nf<2;nf++){
    float s = 0.f;
    #pragma unroll
    for (int fn=0;fn<8;fn++)
      #pragma unroll
      for (int mi=0;mi<4;mi++){
        float e = __expf(acc[nf][fn][mi] * scale);
        acc[nf][fn][mi] = e;
        s += e;
      }
    s += __shfl_xor(s, 16);
    s += __shfl_xor(s, 32);
    sm[nf] = s;
  }
  if (lane < 16){ red[w][lane] = sm[0]; red[w][16 + lane] = sm[1]; }
  __syncthreads();
  float inv[2];
  #pragma unroll
  for (int nf=0;nf<2;nf++){
    float tot = 0.f;
    #pragma unroll
    for (int ww=0; ww<16; ww++) tot += red[ww][nf*16 + lrow];
    inv[nf] = 1.0f / tot;
  }
  float* dst = probs + (size_t)b*SEQ*SEQ;
  #pragma unroll
  for (int nf=0;nf<2;nf++){
    size_t rowoff = (size_t)(i0 + nf*16 + lrow)*SEQ + w*128 + lk*4;
    f32x4 iv = {inv[nf], inv[nf], inv[nf], inv[nf]};
    #pragma unroll
    for (int fn=0;fn<8;fn++){
      f32x4 v = acc[nf][fn] * iv;
      __builtin_nontemporal_store(v, (f32x4*)(dst + rowoff + fn*16));
    }
  }
}

// ---------------- K3: context = probs @ v (fragment-tiled bv loads) ----------------
// 64x512 tile, 256 blocks = 1/CU, 8 waves; round-5 structure + tiled vT.
__global__ __launch_bounds__(512,2) void k_pv(const float* __restrict__ probs, const __half* __restrict__ vT,
                                              float* __restrict__ out0){
  __shared__ __align__(16) _Float16 lA[64*64];   // 8 KB
  int bid = blockIdx.x;
  int b  = bid & 7;            // XCD pin: vT[b] L2-resident
  int i0 = (bid >> 3) * 64;
  int t = threadIdx.x;
  int w = t >> 6, lane = t & 63;
  int lrow = lane & 15, lk = lane >> 4;
  int wm = w >> 2, wn = w & 3;
  int sr = t >> 3, ssc = t & 7;
  int loff = lrow*32 + lk*8;

  const float*  psrc  = probs + ((size_t)b*SEQ + i0 + sr)*SEQ + ssc*8;
  // tiled vT: frag (attn row a0=wn*128+fn*16, keys k0+u*32) at (wn*8+fn)*32768 + ((k0>>5)+u)*512
  const __half* vbase = vT + (size_t)b*ATTN*SEQ + (size_t)wn*8*32768 + loff;
  int dst_sl = (ssc ^ (sr & 7)) * 8;

  f32x4 acc[2][8];
  #pragma unroll
  for (int i=0;i<2;i++)
    #pragma unroll
    for (int j=0;j<8;j++) acc[i][j] = f32x4{0.f,0.f,0.f,0.f};

  float4 p0 = *(const float4*)(psrc);
  float4 p1 = *(const float4*)(psrc + 4);

  for (int k0 = 0; k0 < SEQ; k0 += 64){
    f16x8 hv;
    hv[0]=(_Float16)p0.x; hv[1]=(_Float16)p0.y; hv[2]=(_Float16)p0.z; hv[3]=(_Float16)p0.w;
    hv[4]=(_Float16)p1.x; hv[5]=(_Float16)p1.y; hv[6]=(_Float16)p1.z; hv[7]=(_Float16)p1.w;
    __syncthreads();
    *(f16x8*)&lA[sr*64 + dst_sl] = hv;
    __syncthreads();
    if (k0 + 64 < SEQ){
      p0 = *(const float4*)(psrc + k0 + 64);
      p1 = *(const float4*)(psrc + k0 + 68);
    }
    #pragma unroll
    for (int u=0; u<2; u++){
      f16x8 af[2];
      #pragma unroll
      for (int fm=0; fm<2; fm++){
        int row = wm*32 + fm*16 + lrow;
        af[fm] = *(const f16x8*)&lA[row*64 + (((u*4 + lk) ^ (row & 7))*8)];
      }
      size_t koff = (size_t)((k0 >> 5) + u)*512;
      #pragma unroll
      for (int fn=0; fn<8; fn++){
        f16x8 bv8 = *(const f16x8*)(vbase + (size_t)fn*32768 + koff);
        acc[0][fn] = __builtin_amdgcn_mfma_f32_16x16x32_f16(af[0], bv8, acc[0][fn], 0,0,0);
        acc[1][fn] = __builtin_amdgcn_mfma_f32_16x16x32_f16(af[1], bv8, acc[1][fn], 0,0,0);
      }
    }
  }

  float* dst = out0 + ((size_t)b*SEQ + i0)*ATTN;
  #pragma unroll
  for (int fm=0; fm<2; fm++)
    #pragma unroll
    for (int fn=0; fn<8; fn++)
      #pragma unroll
      for (int mi=0; mi<4; mi++)
        dst[(size_t)(wm*32 + fm*16 + lk*4 + mi)*ATTN + wn*128 + fn*16 + lrow] = tanh_fast(acc[fm][fn][mi]);
}

extern "C" void kernel_launch(void* const* d_in, const int* in_sizes, int n_in,
                              void* d_out, int out_size, void* d_ws, size_t ws_size,
                              hipStream_t stream){
  const float* x  = (const float*)d_in[0];
  const float* Wq = (const float*)d_in[1];
  const float* bq = (const float*)d_in[2];
  const float* Wk = (const float*)d_in[3];
  const float* bk = (const float*)d_in[4];
  const float* Wv = (const float*)d_in[5];
  const float* bv = (const float*)d_in[6];

  float* out0 = (float*)d_out;                        // [8,2048,512]  tanh(context)   33.55 MB
  float* out1 = out0 + (size_t)NB*SEQ*ATTN;           // [8,2048,2048] probs          134.2 MB

  const size_t SZ = 16777216;                         // 16.78 MB
  char* ws = (char*)d_ws;
  // out1 region (written only by k_scores): xh | whT | vh overlay
  __half* xh  = (__half*)out1;
  __half* whT = (__half*)((char*)out1 + 2*SZ);
  __half* vh  = (__half*)((char*)out1 + 2*SZ + 3145728);
  __half* vT  = (__half*)ws;

  if (ws_size >= 3*SZ){
    // qh/kh in d_ws (round 7 confirmed ws_size >= 50.3 MB)
    __half* qh = (__half*)(ws + SZ);
    __half* kh = (__half*)(ws + 2*SZ);
    k_cast_x     <<<8192,        256, 0, stream>>>(x, xh);
    k_transpose_w<<<dim3(512,3), 256, 0, stream>>>(Wq, Wk, Wv, whT);
    k_proj       <<<dim3(12,128),256, 0, stream>>>(xh, whT, bq, bk, bv, qh, kh, vh);
    k_transpose_v<<<dim3(256,8), 256, 0, stream>>>(vh, vT);
    k_scores     <<<512,        1024, 0, stream>>>(qh, kh, out1);
    k_pv         <<<256,         512, 0, stream>>>(out1, vT, out0);
  } else {
    // fallback: qh/kh overlay out0 (safe: out0 written only by k_pv, after qh/kh dead)
    __half* qh = (__half*)out0;
    __half* kh = (__half*)out0 + (size_t)MROWS*ATTN;
    k_cast_x     <<<8192,        256, 0, stream>>>(x, xh);
    k_transpose_w<<<dim3(512,3), 256, 0, stream>>>(Wq, Wk, Wv, whT);
    k_proj       <<<dim3(12,128),256, 0, stream>>>(xh, whT, bq, bk, bv, qh, kh, vh);
    k_transpose_v<<<dim3(256,8), 256, 0, stream>>>(vh, vT);
    k_scores     <<<512,        1024, 0, stream>>>(qh, kh, out1);
    k_pv         <<<256,         512, 0, stream>>>(out1, vT, out0);
  }
}

// Round 10
// 389.616 us; speedup vs baseline: 1.2296x; 1.0060x over previous
//
#include <hip/hip_runtime.h>
#include <hip/hip_fp16.h>
#include <cstdint>

#define HIDDEN 1024
#define ATTN   512
#define NB     8
#define SEQ    2048
#define MROWS  (NB*SEQ)   // 16384

typedef _Float16 f16x8 __attribute__((ext_vector_type(8)));
typedef float    f32x4 __attribute__((ext_vector_type(4)));

// Fragment-major tiled layout for MFMA operands (q/k/vT):
//   addr(r, a) = (r>>4)*8192 + (a>>5)*512 + (r&15)*32 + (a&31)     [halfs]
// => a wave's 16x32 fragment is one contiguous 1KB block.

__device__ __forceinline__ float tanh_fast(float x){
  float e = __expf(2.0f*x);
  return 1.0f - 2.0f/(e + 1.0f);
}

__device__ __forceinline__ void gload16(const void* g, void* l){
  __builtin_amdgcn_global_load_lds((const __attribute__((address_space(1))) void*)g,
                                   (__attribute__((address_space(3))) void*)l, 16, 0, 0);
}

// ---------------- K0a: cast inputs f32 -> fp16 ----------------
__global__ __launch_bounds__(256) void k_cast_x(const float* __restrict__ x, __half* __restrict__ xh){
  size_t i = (size_t)blockIdx.x*256 + threadIdx.x;
  const float4* src = reinterpret_cast<const float4*>(x) + i*2;
  float4 a = src[0], b = src[1];
  f16x8 h;
  h[0]=(_Float16)a.x; h[1]=(_Float16)a.y; h[2]=(_Float16)a.z; h[3]=(_Float16)a.w;
  h[4]=(_Float16)b.x; h[5]=(_Float16)b.y; h[6]=(_Float16)b.z; h[7]=(_Float16)b.w;
  reinterpret_cast<f16x8*>(xh)[i] = h;
}

// ---------------- K0b: W[1024][512] f32 -> WhT[512][1024] fp16 (x3) ----------------
__global__ __launch_bounds__(256) void k_transpose_w(const float* __restrict__ Wq, const float* __restrict__ Wk,
                                                     const float* __restrict__ Wv, __half* __restrict__ whT){
  __shared__ float lds[32][33];
  int which = blockIdx.y;
  const float* W = which==0 ? Wq : (which==1 ? Wk : Wv);
  int tr = blockIdx.x >> 4;
  int tc = blockIdx.x & 15;
  int t = threadIdx.x;
  {
    int r = t >> 3, c4 = (t & 7)*4;
    float4 v = *reinterpret_cast<const float4*>(W + (size_t)(tr*32 + r)*ATTN + tc*32 + c4);
    lds[r][c4+0]=v.x; lds[r][c4+1]=v.y; lds[r][c4+2]=v.z; lds[r][c4+3]=v.w;
  }
  __syncthreads();
  {
    int n = t >> 3, k4 = (t & 7)*4;
    ushort4 u;
    u.x = __half_as_ushort(__float2half(lds[k4+0][n]));
    u.y = __half_as_ushort(__float2half(lds[k4+1][n]));
    u.z = __half_as_ushort(__float2half(lds[k4+2][n]));
    u.w = __half_as_ushort(__float2half(lds[k4+3][n]));
    *reinterpret_cast<ushort4*>(whT + (size_t)which*ATTN*HIDDEN + (size_t)(tc*32 + n)*HIDDEN + tr*32 + k4) = u;
  }
}

// ---------------- K1: fused QKV projection ----------------
// q/k outputs fragment-tiled; v row-major (repacked by k_transpose_v).
__global__ __launch_bounds__(256,3) void k_proj(const __half* __restrict__ xh, const __half* __restrict__ whT,
                                                const float* __restrict__ bq, const float* __restrict__ bk,
                                                const float* __restrict__ bv,
                                                __half* __restrict__ qh, __half* __restrict__ kh, __half* __restrict__ vh){
  __shared__ __align__(16) _Float16 lA[128*64];   // 16 KB
  __shared__ __align__(16) _Float16 lB[128*64];   // 16 KB
  int nt = blockIdx.x;             // 0..11 : which = nt>>2, 128-col slab = nt&3
  int m0 = blockIdx.y * 128;
  int which = nt >> 2;
  int ncol0 = (nt & 3) * 128;
  int t = threadIdx.x;
  int w = t >> 6, lane = t & 63;
  int lrow = lane & 15, lk = lane >> 4;
  int wm = w >> 1, wn = w & 1;

  int rr = lane >> 3;
  int ss = (lane & 7) ^ rr;
  const __half* Abase = xh + (size_t)(m0 + w*32 + rr)*HIDDEN + ss*8;
  const __half* Bbase = whT + (size_t)which*ATTN*HIDDEN + (size_t)(ncol0 + w*32 + rr)*HIDDEN + ss*8;
  _Float16* lAw = &lA[(w*32)*64];
  _Float16* lBw = &lB[(w*32)*64];

  f32x4 acc[4][4];
  #pragma unroll
  for (int i=0;i<4;i++)
    #pragma unroll
    for (int j=0;j<4;j++) acc[i][j] = f32x4{0.f,0.f,0.f,0.f};

  for (int k0 = 0; k0 < HIDDEN; k0 += 64){
    __syncthreads();
    #pragma unroll
    for (int c=0; c<4; c++){
      gload16(Abase + (size_t)c*8*HIDDEN + k0, &lAw[c*8*64]);
      gload16(Bbase + (size_t)c*8*HIDDEN + k0, &lBw[c*8*64]);
    }
    __syncthreads();
    #pragma unroll
    for (int u=0; u<2; u++){
      f16x8 af[4], bf[4];
      #pragma unroll
      for (int fm=0; fm<4; fm++){
        int row = wm*64 + fm*16 + lrow;
        af[fm] = *(const f16x8*)&lA[row*64 + (((u*4 + lk) ^ (row & 7))*8)];
      }
      #pragma unroll
      for (int fn=0; fn<4; fn++){
        int row = wn*64 + fn*16 + lrow;
        bf[fn] = *(const f16x8*)&lB[row*64 + (((u*4 + lk) ^ (row & 7))*8)];
      }
      #pragma unroll
      for (int fm=0; fm<4; fm++)
        #pragma unroll
        for (int fn=0; fn<4; fn++)
          acc[fm][fn] = __builtin_amdgcn_mfma_f32_16x16x32_f16(af[fm], bf[fn], acc[fm][fn], 0,0,0);
    }
  }

  const float* bias = which==0 ? bq : (which==1 ? bk : bv);
  __half* dst = which==0 ? qh : (which==1 ? kh : vh);
  if (which < 2){
    int rt_base = (m0 >> 4) + wm*4;          // + fm
    int at_base = (ncol0 >> 5) + wn*2;       // + (fn>>1)
    #pragma unroll
    for (int fn=0; fn<4; fn++){
      int col = ncol0 + wn*64 + fn*16 + lrow;
      float bb = bias[col];
      int at = at_base + (fn >> 1);
      int asub = (fn & 1)*16 + lrow;
      #pragma unroll
      for (int fm=0; fm<4; fm++){
        size_t tbase = (size_t)(rt_base + fm)*8192 + (size_t)at*512 + asub;
        #pragma unroll
        for (int mi=0; mi<4; mi++)
          dst[tbase + (lk*4 + mi)*32] = __float2half(tanh_fast(acc[fm][fn][mi] + bb));
      }
    }
  } else {
    #pragma unroll
    for (int fn=0; fn<4; fn++){
      int col = ncol0 + wn*64 + fn*16 + lrow;
      float bb = bias[col];
      #pragma unroll
      for (int fm=0; fm<4; fm++)
        #pragma unroll
        for (int mi=0; mi<4; mi++){
          int row = m0 + wm*64 + fm*16 + lk*4 + mi;
          dst[(size_t)row*ATTN + col] = __float2half(tanh_fast(acc[fm][fn][mi] + bb));
        }
    }
  }
}

// ---------------- K1b: vh[16384][512] -> vT tiled [8][512/16][2048/32][16][32] ----------------
__global__ __launch_bounds__(256) void k_transpose_v(const __half* __restrict__ vh, __half* __restrict__ vT){
  __shared__ _Float16 lds[64][80];
  int r0 = blockIdx.x * 64;          // key rows
  int c0 = blockIdx.y * 64;          // attn cols
  int b = r0 / SEQ, j0 = r0 % SEQ;
  int t = threadIdx.x;
  #pragma unroll
  for (int it=0; it<2; it++){
    int g = it*256 + t;
    int r = g >> 3, s = g & 7;
    f16x8 v = *(const f16x8*)(vh + (size_t)(r0 + r)*ATTN + c0 + s*8);
    #pragma unroll
    for (int i=0;i<8;i++) lds[s*8+i][r] = v[i];
  }
  __syncthreads();
  __half* vb = vT + (size_t)b*ATTN*SEQ;
  #pragma unroll
  for (int it=0; it<2; it++){
    int g = it*256 + t;
    int ar = g >> 3, s = g & 7;
    f16x8 v = *(const f16x8*)&lds[ar][s*8];
    int a = c0 + ar;
    int j = j0 + s*8;
    *(f16x8*)(vb + (size_t)(a >> 4)*(16*SEQ) + (size_t)(j >> 5)*512 + (a & 15)*32 + (j & 31)) = v;
  }
}

// ---------------- K2: scores + no-max softmax -> probs (fragment-tiled loads) ----------------
// Plain (cache-allocating) probs stores so k_pv reads hit L2/L3.
__global__ __launch_bounds__(1024,4) void k_scores(const __half* __restrict__ qh, const __half* __restrict__ kh,
                                                   float* __restrict__ probs){
  __shared__ float red[16][32];
  int bid = blockIdx.x;
  int b  = bid & 7;            // XCD pin
  int i0 = (bid >> 3) * 32;
  int t = threadIdx.x;
  int w = t >> 6, lane = t & 63;
  int lrow = lane & 15, lk = lane >> 4;
  int loff = lrow*32 + lk*8;

  const __half* kbase = kh + (size_t)((b*SEQ + w*128) >> 4)*8192 + loff;  // +fn*8192 + it*512
  const __half* qbase = qh + (size_t)((b*SEQ + i0) >> 4)*8192 + loff;     // +nf*8192 + it*512

  f32x4 acc[2][8];
  #pragma unroll
  for (int i=0;i<2;i++)
    #pragma unroll
    for (int j=0;j<8;j++) acc[i][j] = f32x4{0.f,0.f,0.f,0.f};

  for (int it = 0; it < 16; it++){
    f16x8 aq0 = *(const f16x8*)(qbase + it*512);
    f16x8 aq1 = *(const f16x8*)(qbase + 8192 + it*512);
    #pragma unroll
    for (int fn=0; fn<8; fn++){
      f16x8 kf = *(const f16x8*)(kbase + (size_t)fn*8192 + it*512);
      acc[0][fn] = __builtin_amdgcn_mfma_f32_16x16x32_f16(kf, aq0, acc[0][fn], 0,0,0);
      acc[1][fn] = __builtin_amdgcn_mfma_f32_16x16x32_f16(kf, aq1, acc[1][fn], 0,0,0);
    }
  }

  // no-max softmax: |s*scale| <= 22.63, f32-safe (verified rounds 7-9)
  const float scale = 0.044194173824159216f;   // 1/sqrt(512)
  float sm[2];
  #pragma unroll
  for (int nf=0;nf<2;nf++){
    float s = 0.f;
    #pragma unroll
    for (int fn=0;fn<8;fn++)
      #pragma unroll
      for (int mi=0;mi<4;mi++){
        float e = __expf(acc[nf][fn][mi] * scale);
        acc[nf][fn][mi] = e;
        s += e;
      }
    s += __shfl_xor(s, 16);
    s += __shfl_xor(s, 32);
    sm[nf] = s;
  }
  if (lane < 16){ red[w][lane] = sm[0]; red[w][16 + lane] = sm[1]; }
  __syncthreads();
  float inv[2];
  #pragma unroll
  for (int nf=0;nf<2;nf++){
    float tot = 0.f;
    #pragma unroll
    for (int ww=0; ww<16; ww++) tot += red[ww][nf*16 + lrow];
    inv[nf] = 1.0f / tot;
  }
  float* dst = probs + (size_t)b*SEQ*SEQ;
  #pragma unroll
  for (int nf=0;nf<2;nf++){
    size_t rowoff = (size_t)(i0 + nf*16 + lrow)*SEQ + w*128 + lk*4;
    f32x4 iv = {inv[nf], inv[nf], inv[nf], inv[nf]};
    #pragma unroll
    for (int fn=0;fn<8;fn++){
      f32x4 v = acc[nf][fn] * iv;
      *(f32x4*)(dst + rowoff + fn*16) = v;
    }
  }
}

// ---------------- K3: context = probs @ v — barrier-free, direct probs reads ----------------
// 512 blocks (2/CU), 512 thr (8 waves). Block: 32 q-rows x 512 cols; wave w: cols [w*64, w*64+64).
// A-frag: lane reads 8 consecutive f32 of its q-row (2 x float4, 4 lanes/128B segment), cvt fp16.
// B-frags from tiled vT (1KB single-segment). No LDS, no barriers -> waves free-run.
__global__ __launch_bounds__(512,4) void k_pv(const float* __restrict__ probs, const __half* __restrict__ vT,
                                              float* __restrict__ out0){
  int bid = blockIdx.x;
  int b  = bid & 7;            // XCD pin: vT[b] L2-resident; same XCD wrote these probs rows
  int i0 = (bid >> 3) * 32;
  int t = threadIdx.x;
  int w = t >> 6, lane = t & 63;
  int lrow = lane & 15, lk = lane >> 4;
  int loff = lrow*32 + lk*8;

  const float* pbase = probs + ((size_t)b*SEQ + i0 + lrow)*SEQ + lk*8;   // + nf*16*SEQ + k0
  const __half* vbase = vT + (size_t)b*ATTN*SEQ + (size_t)(w*4)*32768 + loff;  // + cf*32768 + kt*512

  f32x4 acc[2][4];
  #pragma unroll
  for (int i=0;i<2;i++)
    #pragma unroll
    for (int j=0;j<4;j++) acc[i][j] = f32x4{0.f,0.f,0.f,0.f};

  for (int kt = 0; kt < 64; kt++){
    int k0 = kt*32;
    f16x8 af[2];
    #pragma unroll
    for (int nf=0; nf<2; nf++){
      const float* pr = pbase + (size_t)nf*16*SEQ + k0;
      float4 a = *(const float4*)(pr);
      float4 c = *(const float4*)(pr + 4);
      f16x8 h;
      h[0]=(_Float16)a.x; h[1]=(_Float16)a.y; h[2]=(_Float16)a.z; h[3]=(_Float16)a.w;
      h[4]=(_Float16)c.x; h[5]=(_Float16)c.y; h[6]=(_Float16)c.z; h[7]=(_Float16)c.w;
      af[nf] = h;
    }
    #pragma unroll
    for (int cf=0; cf<4; cf++){
      f16x8 bv8 = *(const f16x8*)(vbase + (size_t)cf*32768 + kt*512);
      acc[0][cf] = __builtin_amdgcn_mfma_f32_16x16x32_f16(af[0], bv8, acc[0][cf], 0,0,0);
      acc[1][cf] = __builtin_amdgcn_mfma_f32_16x16x32_f16(af[1], bv8, acc[1][cf], 0,0,0);
    }
  }

  float* dst = out0 + ((size_t)b*SEQ + i0)*ATTN + w*64;
  #pragma unroll
  for (int nf=0; nf<2; nf++)
    #pragma unroll
    for (int cf=0; cf<4; cf++)
      #pragma unroll
      for (int mi=0; mi<4; mi++)
        dst[(size_t)(nf*16 + lk*4 + mi)*ATTN + cf*16 + lrow] = tanh_fast(acc[nf][cf][mi]);
}

extern "C" void kernel_launch(void* const* d_in, const int* in_sizes, int n_in,
                              void* d_out, int out_size, void* d_ws, size_t ws_size,
                              hipStream_t stream){
  const float* x  = (const float*)d_in[0];
  const float* Wq = (const float*)d_in[1];
  const float* bq = (const float*)d_in[2];
  const float* Wk = (const float*)d_in[3];
  const float* bk = (const float*)d_in[4];
  const float* Wv = (const float*)d_in[5];
  const float* bv = (const float*)d_in[6];

  float* out0 = (float*)d_out;                        // [8,2048,512]  tanh(context)   33.55 MB
  float* out1 = out0 + (size_t)NB*SEQ*ATTN;           // [8,2048,2048] probs          134.2 MB

  const size_t SZ = 16777216;                         // 16.78 MB
  char* ws = (char*)d_ws;
  // out1 region (written only by k_scores): xh | whT | vh overlay
  __half* xh  = (__half*)out1;
  __half* whT = (__half*)((char*)out1 + 2*SZ);
  __half* vh  = (__half*)((char*)out1 + 2*SZ + 3145728);
  __half* vT  = (__half*)ws;

  if (ws_size >= 3*SZ){
    // qh/kh in d_ws (round 7 confirmed ws_size >= 50.3 MB)
    __half* qh = (__half*)(ws + SZ);
    __half* kh = (__half*)(ws + 2*SZ);
    k_cast_x     <<<8192,        256, 0, stream>>>(x, xh);
    k_transpose_w<<<dim3(512,3), 256, 0, stream>>>(Wq, Wk, Wv, whT);
    k_proj       <<<dim3(12,128),256, 0, stream>>>(xh, whT, bq, bk, bv, qh, kh, vh);
    k_transpose_v<<<dim3(256,8), 256, 0, stream>>>(vh, vT);
    k_scores     <<<512,        1024, 0, stream>>>(qh, kh, out1);
    k_pv         <<<512,         512, 0, stream>>>(out1, vT, out0);
  } else {
    // fallback: qh/kh overlay out0 (safe: out0 written only by k_pv, after qh/kh dead)
    __half* qh = (__half*)out0;
    __half* kh = (__half*)out0 + (size_t)MROWS*ATTN;
    k_cast_x     <<<8192,        256, 0, stream>>>(x, xh);
    k_transpose_w<<<dim3(512,3), 256, 0, stream>>>(Wq, Wk, Wv, whT);
    k_proj       <<<dim3(12,128),256, 0, stream>>>(xh, whT, bq, bk, bv, qh, kh, vh);
    k_transpose_v<<<dim3(256,8), 256, 0, stream>>>(vh, vT);
    k_scores     <<<512,        1024, 0, stream>>>(qh, kh, out1);
    k_pv         <<<512,         512, 0, stream>>>(out1, vT, out0);
  }
}

// Round 12
// 311.700 us; speedup vs baseline: 1.5370x; 1.2500x over previous
//
#include <hip/hip_runtime.h>
#include <hip/hip_fp16.h>
#include <cstdint>

#define HIDDEN 1024
#define ATTN   512
#define NB     8
#define SEQ    2048
#define MROWS  (NB*SEQ)   // 16384

typedef _Float16 f16x8 __attribute__((ext_vector_type(8)));
typedef _Float16 f16x4 __attribute__((ext_vector_type(4)));
typedef float    f32x4 __attribute__((ext_vector_type(4)));

// Fragment-major tiled layout for all fp16 MFMA operands (q/k/vT/P16):
//   addr(r, c) = (r>>4)*(16*C) + (c>>5)*512 + (r&15)*32 + (c&31)   [halfs]
// => a wave's 16x32 fragment is one contiguous 1KB block (single-segment load).

__device__ __forceinline__ float tanh_fast(float x){
  float e = __expf(2.0f*x);
  return 1.0f - 2.0f/(e + 1.0f);
}

__device__ __forceinline__ void gload16(const void* g, void* l){
  __builtin_amdgcn_global_load_lds((const __attribute__((address_space(1))) void*)g,
                                   (__attribute__((address_space(3))) void*)l, 16, 0, 0);
}

// ---------------- K0a: cast inputs f32 -> fp16 ----------------
__global__ __launch_bounds__(256) void k_cast_x(const float* __restrict__ x, __half* __restrict__ xh){
  size_t i = (size_t)blockIdx.x*256 + threadIdx.x;
  const float4* src = reinterpret_cast<const float4*>(x) + i*2;
  float4 a = src[0], b = src[1];
  f16x8 h;
  h[0]=(_Float16)a.x; h[1]=(_Float16)a.y; h[2]=(_Float16)a.z; h[3]=(_Float16)a.w;
  h[4]=(_Float16)b.x; h[5]=(_Float16)b.y; h[6]=(_Float16)b.z; h[7]=(_Float16)b.w;
  reinterpret_cast<f16x8*>(xh)[i] = h;
}

// ---------------- K0b: W[1024][512] f32 -> WhT[512][1024] fp16 (x3) ----------------
__global__ __launch_bounds__(256) void k_transpose_w(const float* __restrict__ Wq, const float* __restrict__ Wk,
                                                     const float* __restrict__ Wv, __half* __restrict__ whT){
  __shared__ float lds[32][33];
  int which = blockIdx.y;
  const float* W = which==0 ? Wq : (which==1 ? Wk : Wv);
  int tr = blockIdx.x >> 4;
  int tc = blockIdx.x & 15;
  int t = threadIdx.x;
  {
    int r = t >> 3, c4 = (t & 7)*4;
    float4 v = *reinterpret_cast<const float4*>(W + (size_t)(tr*32 + r)*ATTN + tc*32 + c4);
    lds[r][c4+0]=v.x; lds[r][c4+1]=v.y; lds[r][c4+2]=v.z; lds[r][c4+3]=v.w;
  }
  __syncthreads();
  {
    int n = t >> 3, k4 = (t & 7)*4;
    ushort4 u;
    u.x = __half_as_ushort(__float2half(lds[k4+0][n]));
    u.y = __half_as_ushort(__float2half(lds[k4+1][n]));
    u.z = __half_as_ushort(__float2half(lds[k4+2][n]));
    u.w = __half_as_ushort(__float2half(lds[k4+3][n]));
    *reinterpret_cast<ushort4*>(whT + (size_t)which*ATTN*HIDDEN + (size_t)(tc*32 + n)*HIDDEN + tr*32 + k4) = u;
  }
}

// ---------------- K1: fused QKV projection ----------------
// q/k outputs fragment-tiled; v row-major (repacked by k_transpose_v).
__global__ __launch_bounds__(256,3) void k_proj(const __half* __restrict__ xh, const __half* __restrict__ whT,
                                                const float* __restrict__ bq, const float* __restrict__ bk,
                                                const float* __restrict__ bv,
                                                __half* __restrict__ qh, __half* __restrict__ kh, __half* __restrict__ vh){
  __shared__ __align__(16) _Float16 lA[128*64];   // 16 KB
  __shared__ __align__(16) _Float16 lB[128*64];   // 16 KB
  int nt = blockIdx.x;             // 0..11 : which = nt>>2, 128-col slab = nt&3
  int m0 = blockIdx.y * 128;
  int which = nt >> 2;
  int ncol0 = (nt & 3) * 128;
  int t = threadIdx.x;
  int w = t >> 6, lane = t & 63;
  int lrow = lane & 15, lk = lane >> 4;
  int wm = w >> 1, wn = w & 1;

  int rr = lane >> 3;
  int ss = (lane & 7) ^ rr;
  const __half* Abase = xh + (size_t)(m0 + w*32 + rr)*HIDDEN + ss*8;
  const __half* Bbase = whT + (size_t)which*ATTN*HIDDEN + (size_t)(ncol0 + w*32 + rr)*HIDDEN + ss*8;
  _Float16* lAw = &lA[(w*32)*64];
  _Float16* lBw = &lB[(w*32)*64];

  f32x4 acc[4][4];
  #pragma unroll
  for (int i=0;i<4;i++)
    #pragma unroll
    for (int j=0;j<4;j++) acc[i][j] = f32x4{0.f,0.f,0.f,0.f};

  for (int k0 = 0; k0 < HIDDEN; k0 += 64){
    __syncthreads();
    #pragma unroll
    for (int c=0; c<4; c++){
      gload16(Abase + (size_t)c*8*HIDDEN + k0, &lAw[c*8*64]);
      gload16(Bbase + (size_t)c*8*HIDDEN + k0, &lBw[c*8*64]);
    }
    __syncthreads();
    #pragma unroll
    for (int u=0; u<2; u++){
      f16x8 af[4], bf[4];
      #pragma unroll
      for (int fm=0; fm<4; fm++){
        int row = wm*64 + fm*16 + lrow;
        af[fm] = *(const f16x8*)&lA[row*64 + (((u*4 + lk) ^ (row & 7))*8)];
      }
      #pragma unroll
      for (int fn=0; fn<4; fn++){
        int row = wn*64 + fn*16 + lrow;
        bf[fn] = *(const f16x8*)&lB[row*64 + (((u*4 + lk) ^ (row & 7))*8)];
      }
      #pragma unroll
      for (int fm=0; fm<4; fm++)
        #pragma unroll
        for (int fn=0; fn<4; fn++)
          acc[fm][fn] = __builtin_amdgcn_mfma_f32_16x16x32_f16(af[fm], bf[fn], acc[fm][fn], 0,0,0);
    }
  }

  const float* bias = which==0 ? bq : (which==1 ? bk : bv);
  __half* dst = which==0 ? qh : (which==1 ? kh : vh);
  if (which < 2){
    int rt_base = (m0 >> 4) + wm*4;          // + fm
    int at_base = (ncol0 >> 5) + wn*2;       // + (fn>>1)
    #pragma unroll
    for (int fn=0; fn<4; fn++){
      int col = ncol0 + wn*64 + fn*16 + lrow;
      float bb = bias[col];
      int at = at_base + (fn >> 1);
      int asub = (fn & 1)*16 + lrow;
      #pragma unroll
      for (int fm=0; fm<4; fm++){
        size_t tbase = (size_t)(rt_base + fm)*8192 + (size_t)at*512 + asub;
        #pragma unroll
        for (int mi=0; mi<4; mi++)
          dst[tbase + (lk*4 + mi)*32] = __float2half(tanh_fast(acc[fm][fn][mi] + bb));
      }
    }
  } else {
    #pragma unroll
    for (int fn=0; fn<4; fn++){
      int col = ncol0 + wn*64 + fn*16 + lrow;
      float bb = bias[col];
      #pragma unroll
      for (int fm=0; fm<4; fm++)
        #pragma unroll
        for (int mi=0; mi<4; mi++){
          int row = m0 + wm*64 + fm*16 + lk*4 + mi;
          dst[(size_t)row*ATTN + col] = __float2half(tanh_fast(acc[fm][fn][mi] + bb));
        }
    }
  }
}

// ---------------- K1b: vh[16384][512] -> vT tiled [8][512/16][2048/32][16][32] ----------------
__global__ __launch_bounds__(256) void k_transpose_v(const __half* __restrict__ vh, __half* __restrict__ vT){
  __shared__ _Float16 lds[64][80];
  int r0 = blockIdx.x * 64;          // key rows
  int c0 = blockIdx.y * 64;          // attn cols
  int b = r0 / SEQ, j0 = r0 % SEQ;
  int t = threadIdx.x;
  #pragma unroll
  for (int it=0; it<2; it++){
    int g = it*256 + t;
    int r = g >> 3, s = g & 7;
    f16x8 v = *(const f16x8*)(vh + (size_t)(r0 + r)*ATTN + c0 + s*8);
    #pragma unroll
    for (int i=0;i<8;i++) lds[s*8+i][r] = v[i];
  }
  __syncthreads();
  __half* vb = vT + (size_t)b*ATTN*SEQ;
  #pragma unroll
  for (int it=0; it<2; it++){
    int g = it*256 + t;
    int ar = g >> 3, s = g & 7;
    f16x8 v = *(const f16x8*)&lds[ar][s*8];
    int a = c0 + ar;
    int j = j0 + s*8;
    *(f16x8*)(vb + (size_t)(a >> 4)*(16*SEQ) + (size_t)(j >> 5)*512 + (a & 15)*32 + (j & 31)) = v;
  }
}

// ---------------- K2: scores + no-max softmax ----------------
// Main path (p16 != null, probs == null): write ONLY tiled-fp16 P16 (67 MB).
// Fallback (probs != null, p16 == null): round-10 behavior, plain f32 probs stores.
__global__ __launch_bounds__(1024,4) void k_scores(const __half* __restrict__ qh, const __half* __restrict__ kh,
                                                   float* __restrict__ probs, __half* __restrict__ p16){
  __shared__ float red[16][32];
  int bid = blockIdx.x;
  int b  = bid & 7;            // XCD pin
  int i0 = (bid >> 3) * 32;
  int t = threadIdx.x;
  int w = t >> 6, lane = t & 63;
  int lrow = lane & 15, lk = lane >> 4;
  int loff = lrow*32 + lk*8;

  const __half* kbase = kh + (size_t)((b*SEQ + w*128) >> 4)*8192 + loff;  // +fn*8192 + it*512
  const __half* qbase = qh + (size_t)((b*SEQ + i0) >> 4)*8192 + loff;     // +nf*8192 + it*512

  f32x4 acc[2][8];
  #pragma unroll
  for (int i=0;i<2;i++)
    #pragma unroll
    for (int j=0;j<8;j++) acc[i][j] = f32x4{0.f,0.f,0.f,0.f};

  for (int it = 0; it < 16; it++){
    f16x8 aq0 = *(const f16x8*)(qbase + it*512);
    f16x8 aq1 = *(const f16x8*)(qbase + 8192 + it*512);
    #pragma unroll
    for (int fn=0; fn<8; fn++){
      f16x8 kf = *(const f16x8*)(kbase + (size_t)fn*8192 + it*512);
      acc[0][fn] = __builtin_amdgcn_mfma_f32_16x16x32_f16(kf, aq0, acc[0][fn], 0,0,0);
      acc[1][fn] = __builtin_amdgcn_mfma_f32_16x16x32_f16(kf, aq1, acc[1][fn], 0,0,0);
    }
  }

  // no-max softmax: |s*scale| <= 22.63, f32-safe (verified rounds 7-11)
  const float scale = 0.044194173824159216f;   // 1/sqrt(512)
  float sm[2];
  #pragma unroll
  for (int nf=0;nf<2;nf++){
    float s = 0.f;
    #pragma unroll
    for (int fn=0;fn<8;fn++)
      #pragma unroll
      for (int mi=0;mi<4;mi++){
        float e = __expf(acc[nf][fn][mi] * scale);
        acc[nf][fn][mi] = e;
        s += e;
      }
    s += __shfl_xor(s, 16);
    s += __shfl_xor(s, 32);
    sm[nf] = s;
  }
  if (lane < 16){ red[w][lane] = sm[0]; red[w][16 + lane] = sm[1]; }
  __syncthreads();
  float inv[2];
  #pragma unroll
  for (int nf=0;nf<2;nf++){
    float tot = 0.f;
    #pragma unroll
    for (int ww=0; ww<16; ww++) tot += red[ww][nf*16 + lrow];
    inv[nf] = 1.0f / tot;
  }
  #pragma unroll
  for (int nf=0;nf<2;nf++){
    f32x4 iv = {inv[nf], inv[nf], inv[nf], inv[nf]};
    size_t tq = (size_t)((i0 >> 4) + nf);
    #pragma unroll
    for (int fn=0;fn<8;fn++){
      f32x4 v = acc[nf][fn] * iv;
      if (probs){
        size_t rowoff = (size_t)(i0 + nf*16 + lrow)*SEQ + w*128 + lk*4;
        *(f32x4*)(probs + (size_t)b*SEQ*SEQ + rowoff + fn*16) = v;
      }
      if (p16){
        f16x4 h;
        h[0]=(_Float16)v[0]; h[1]=(_Float16)v[1]; h[2]=(_Float16)v[2]; h[3]=(_Float16)v[3];
        *(f16x4*)&p16[(size_t)b*SEQ*SEQ + tq*32768 + (size_t)(w*4 + (fn>>1))*512 + lrow*32 + (fn&1)*16 + lk*4] = h;
      }
    }
  }
}

// ---------------- K3main: context + probs expansion, all operands fragment-tiled ----------------
// 512 blocks (2/CU), 512 thr (8 waves). Block: 32 q-rows x 512 cols; wave w: cols [w*64, +64).
// Every load (P16 A-frag, vT B-frag) is one contiguous 1KB block. No LDS, no barriers.
// Wave w also expands P16 -> f32 probs (NT) for key-tiles kt in [w*8, w*8+8).
__global__ __launch_bounds__(512,4) void k_pv_p16(const __half* __restrict__ p16, const __half* __restrict__ vT,
                                                  float* __restrict__ probs, float* __restrict__ out0){
  int bid = blockIdx.x;
  int b  = bid & 7;            // XCD pin
  int i0 = (bid >> 3) * 32;
  int t = threadIdx.x;
  int w = t >> 6, lane = t & 63;
  int lrow = lane & 15, lk = lane >> 4;
  int loff = lrow*32 + lk*8;

  const __half* pbase = p16 + (size_t)b*SEQ*SEQ + (size_t)(i0 >> 4)*32768 + loff;   // + nf*32768 + kt*512
  const __half* vbase = vT + (size_t)b*ATTN*SEQ + (size_t)(w*4)*32768 + loff;        // + cf*32768 + kt*512
  float* prow = probs + ((size_t)b*SEQ + i0 + lrow)*SEQ + lk*8;                      // + nf*16*SEQ + kt*32

  f32x4 acc[2][4];
  #pragma unroll
  for (int i=0;i<2;i++)
    #pragma unroll
    for (int j=0;j<4;j++) acc[i][j] = f32x4{0.f,0.f,0.f,0.f};

  for (int kt = 0; kt < 64; kt++){
    f16x8 pa[2];
    #pragma unroll
    for (int nf=0; nf<2; nf++)
      pa[nf] = *(const f16x8*)(pbase + (size_t)nf*32768 + kt*512);
    if ((kt >> 3) == w){   // this wave expands these key-tiles to f32 probs
      #pragma unroll
      for (int nf=0; nf<2; nf++){
        f32x4 lo = {(float)pa[nf][0], (float)pa[nf][1], (float)pa[nf][2], (float)pa[nf][3]};
        f32x4 hi = {(float)pa[nf][4], (float)pa[nf][5], (float)pa[nf][6], (float)pa[nf][7]};
        float* pr = prow + (size_t)nf*16*SEQ + kt*32;
        __builtin_nontemporal_store(lo, (f32x4*)(pr));
        __builtin_nontemporal_store(hi, (f32x4*)(pr + 4));
      }
    }
    #pragma unroll
    for (int cf=0; cf<4; cf++){
      f16x8 bv8 = *(const f16x8*)(vbase + (size_t)cf*32768 + kt*512);
      acc[0][cf] = __builtin_amdgcn_mfma_f32_16x16x32_f16(pa[0], bv8, acc[0][cf], 0,0,0);
      acc[1][cf] = __builtin_amdgcn_mfma_f32_16x16x32_f16(pa[1], bv8, acc[1][cf], 0,0,0);
    }
  }

  float* dst = out0 + ((size_t)b*SEQ + i0)*ATTN + w*64;
  #pragma unroll
  for (int nf=0; nf<2; nf++)
    #pragma unroll
    for (int cf=0; cf<4; cf++)
      #pragma unroll
      for (int mi=0; mi<4; mi++)
        dst[(size_t)(nf*16 + lk*4 + mi)*ATTN + cf*16 + lrow] = tanh_fast(acc[nf][cf][mi]);
}

// ---------------- K3 fallback: context = probs(f32) @ v — round-10 version ----------------
__global__ __launch_bounds__(512,4) void k_pv(const float* __restrict__ probs, const __half* __restrict__ vT,
                                              float* __restrict__ out0){
  int bid = blockIdx.x;
  int b  = bid & 7;
  int i0 = (bid >> 3) * 32;
  int t = threadIdx.x;
  int w = t >> 6, lane = t & 63;
  int lrow = lane & 15, lk = lane >> 4;
  int loff = lrow*32 + lk*8;

  const float* pbase = probs + ((size_t)b*SEQ + i0 + lrow)*SEQ + lk*8;
  const __half* vbase = vT + (size_t)b*ATTN*SEQ + (size_t)(w*4)*32768 + loff;

  f32x4 acc[2][4];
  #pragma unroll
  for (int i=0;i<2;i++)
    #pragma unroll
    for (int j=0;j<4;j++) acc[i][j] = f32x4{0.f,0.f,0.f,0.f};

  for (int kt = 0; kt < 64; kt++){
    int k0 = kt*32;
    f16x8 af[2];
    #pragma unroll
    for (int nf=0; nf<2; nf++){
      const float* pr = pbase + (size_t)nf*16*SEQ + k0;
      float4 a = *(const float4*)(pr);
      float4 c = *(const float4*)(pr + 4);
      f16x8 h;
      h[0]=(_Float16)a.x; h[1]=(_Float16)a.y; h[2]=(_Float16)a.z; h[3]=(_Float16)a.w;
      h[4]=(_Float16)c.x; h[5]=(_Float16)c.y; h[6]=(_Float16)c.z; h[7]=(_Float16)c.w;
      af[nf] = h;
    }
    #pragma unroll
    for (int cf=0; cf<4; cf++){
      f16x8 bv8 = *(const f16x8*)(vbase + (size_t)cf*32768 + kt*512);
      acc[0][cf] = __builtin_amdgcn_mfma_f32_16x16x32_f16(af[0], bv8, acc[0][cf], 0,0,0);
      acc[1][cf] = __builtin_amdgcn_mfma_f32_16x16x32_f16(af[1], bv8, acc[1][cf], 0,0,0);
    }
  }

  float* dst = out0 + ((size_t)b*SEQ + i0)*ATTN + w*64;
  #pragma unroll
  for (int nf=0; nf<2; nf++)
    #pragma unroll
    for (int cf=0; cf<4; cf++)
      #pragma unroll
      for (int mi=0; mi<4; mi++)
        dst[(size_t)(nf*16 + lk*4 + mi)*ATTN + cf*16 + lrow] = tanh_fast(acc[nf][cf][mi]);
}

extern "C" void kernel_launch(void* const* d_in, const int* in_sizes, int n_in,
                              void* d_out, int out_size, void* d_ws, size_t ws_size,
                              hipStream_t stream){
  const float* x  = (const float*)d_in[0];
  const float* Wq = (const float*)d_in[1];
  const float* bq = (const float*)d_in[2];
  const float* Wk = (const float*)d_in[3];
  const float* bk = (const float*)d_in[4];
  const float* Wv = (const float*)d_in[5];
  const float* bv = (const float*)d_in[6];

  float* out0 = (float*)d_out;                        // [8,2048,512]  tanh(context)   33.55 MB
  float* out1 = out0 + (size_t)NB*SEQ*ATTN;           // [8,2048,2048] probs          134.2 MB

  const size_t SZ = 16777216;                         // 16.78 MB
  char* ws = (char*)d_ws;

  if (ws_size >= 5*SZ){
    // MAIN path. ws: vT | p16. out1 scratch: xh | whT | vh | qh | kh (all dead
    // before k_pv_p16 overwrites out1 with probs). out0 written ONCE, by the
    // final kernel. No output doubles as scratch for itself.
    __half* vT  = (__half*)ws;                           // 16.78 MB tiled
    __half* p16 = (__half*)(ws + SZ);                    // 67.1 MB tiled
    __half* xh  = (__half*)out1;                         // 33.55 MB
    __half* whT = (__half*)((char*)out1 + 2*SZ);         // 3.15 MB
    __half* vh  = (__half*)((char*)out1 + 2*SZ + 3145728);          // 16.78 MB
    __half* qh  = (__half*)((char*)out1 + 3*SZ + 3145728);          // 16.78 MB tiled
    __half* kh  = (__half*)((char*)out1 + 4*SZ + 3145728);          // 16.78 MB tiled -> ends 87 MB < 134 MB
    k_cast_x     <<<8192,        256, 0, stream>>>(x, xh);
    k_transpose_w<<<dim3(512,3), 256, 0, stream>>>(Wq, Wk, Wv, whT);
    k_proj       <<<dim3(12,128),256, 0, stream>>>(xh, whT, bq, bk, bv, qh, kh, vh);
    k_transpose_v<<<dim3(256,8), 256, 0, stream>>>(vh, vT);
    k_scores     <<<512,        1024, 0, stream>>>(qh, kh, (float*)nullptr, p16);
    k_pv_p16     <<<512,         512, 0, stream>>>(p16, vT, out1, out0);
  } else if (ws_size >= 3*SZ){
    // round-10 fallback: qh/kh in ws, f32-probs-reading k_pv  (passed @389 us)
    __half* vT = (__half*)ws;
    __half* qh = (__half*)(ws + SZ);
    __half* kh = (__half*)(ws + 2*SZ);
    __half* xh  = (__half*)out1;
    __half* whT = (__half*)((char*)out1 + 2*SZ);
    __half* vh  = (__half*)((char*)out1 + 2*SZ + 3145728);
    k_cast_x     <<<8192,        256, 0, stream>>>(x, xh);
    k_transpose_w<<<dim3(512,3), 256, 0, stream>>>(Wq, Wk, Wv, whT);
    k_proj       <<<dim3(12,128),256, 0, stream>>>(xh, whT, bq, bk, bv, qh, kh, vh);
    k_transpose_v<<<dim3(256,8), 256, 0, stream>>>(vh, vT);
    k_scores     <<<512,        1024, 0, stream>>>(qh, kh, out1, ((__half*)nullptr));
    k_pv         <<<512,         512, 0, stream>>>(out1, vT, out0);
  } else {
    // minimal-ws fallback: qh/kh overlay out0
    __half* vT = (__half*)ws;
    __half* qh = (__half*)out0;
    __half* kh = (__half*)out0 + (size_t)MROWS*ATTN;
    __half* xh  = (__half*)out1;
    __half* whT = (__half*)((char*)out1 + 2*SZ);
    __half* vh  = (__half*)((char*)out1 + 2*SZ + 3145728);
    k_cast_x     <<<8192,        256, 0, stream>>>(x, xh);
    k_transpose_w<<<dim3(512,3), 256, 0, stream>>>(Wq, Wk, Wv, whT);
    k_proj       <<<dim3(12,128),256, 0, stream>>>(xh, whT, bq, bk, bv, qh, kh, vh);
    k_transpose_v<<<dim3(256,8), 256, 0, stream>>>(vh, vT);
    k_scores     <<<512,        1024, 0, stream>>>(qh, kh, out1, ((__half*)nullptr));
    k_pv         <<<512,         512, 0, stream>>>(out1, vT, out0);
  }
}

// Round 13
// 288.338 us; speedup vs baseline: 1.6615x; 1.0810x over previous
//
#include <hip/hip_runtime.h>
#include <hip/hip_fp16.h>
#include <cstdint>

#define HIDDEN 1024
#define ATTN   512
#define NB     8
#define SEQ    2048
#define MROWS  (NB*SEQ)   // 16384

typedef _Float16 f16x8 __attribute__((ext_vector_type(8)));
typedef _Float16 f16x4 __attribute__((ext_vector_type(4)));
typedef float    f32x4 __attribute__((ext_vector_type(4)));

// Fragment-major tiled layout for all fp16 MFMA operands (q/k/vT/P16):
//   addr(r, c) = (r>>4)*(16*C) + (c>>5)*512 + (r&15)*32 + (c&31)   [halfs]
// => a wave's 16x32 fragment is one contiguous 1KB block (single-segment load).

__device__ __forceinline__ float tanh_fast(float x){
  float e = __expf(2.0f*x);
  return 1.0f - 2.0f/(e + 1.0f);
}

__device__ __forceinline__ void gload16(const void* g, void* l){
  __builtin_amdgcn_global_load_lds((const __attribute__((address_space(1))) void*)g,
                                   (__attribute__((address_space(3))) void*)l, 16, 0, 0);
}

// ---------------- K0a: cast inputs f32 -> fp16 ----------------
__global__ __launch_bounds__(256) void k_cast_x(const float* __restrict__ x, __half* __restrict__ xh){
  size_t i = (size_t)blockIdx.x*256 + threadIdx.x;
  const float4* src = reinterpret_cast<const float4*>(x) + i*2;
  float4 a = src[0], b = src[1];
  f16x8 h;
  h[0]=(_Float16)a.x; h[1]=(_Float16)a.y; h[2]=(_Float16)a.z; h[3]=(_Float16)a.w;
  h[4]=(_Float16)b.x; h[5]=(_Float16)b.y; h[6]=(_Float16)b.z; h[7]=(_Float16)b.w;
  reinterpret_cast<f16x8*>(xh)[i] = h;
}

// ---------------- K0b: W[1024][512] f32 -> WhT[512][1024] fp16 (x3) ----------------
__global__ __launch_bounds__(256) void k_transpose_w(const float* __restrict__ Wq, const float* __restrict__ Wk,
                                                     const float* __restrict__ Wv, __half* __restrict__ whT){
  __shared__ float lds[32][33];
  int which = blockIdx.y;
  const float* W = which==0 ? Wq : (which==1 ? Wk : Wv);
  int tr = blockIdx.x >> 4;
  int tc = blockIdx.x & 15;
  int t = threadIdx.x;
  {
    int r = t >> 3, c4 = (t & 7)*4;
    float4 v = *reinterpret_cast<const float4*>(W + (size_t)(tr*32 + r)*ATTN + tc*32 + c4);
    lds[r][c4+0]=v.x; lds[r][c4+1]=v.y; lds[r][c4+2]=v.z; lds[r][c4+3]=v.w;
  }
  __syncthreads();
  {
    int n = t >> 3, k4 = (t & 7)*4;
    ushort4 u;
    u.x = __half_as_ushort(__float2half(lds[k4+0][n]));
    u.y = __half_as_ushort(__float2half(lds[k4+1][n]));
    u.z = __half_as_ushort(__float2half(lds[k4+2][n]));
    u.w = __half_as_ushort(__float2half(lds[k4+3][n]));
    *reinterpret_cast<ushort4*>(whT + (size_t)which*ATTN*HIDDEN + (size_t)(tc*32 + n)*HIDDEN + tr*32 + k4) = u;
  }
}

// ---------------- K1: fused QKV projection ----------------
// q/k outputs fragment-tiled; v row-major (repacked by k_transpose_v).
__global__ __launch_bounds__(256,3) void k_proj(const __half* __restrict__ xh, const __half* __restrict__ whT,
                                                const float* __restrict__ bq, const float* __restrict__ bk,
                                                const float* __restrict__ bv,
                                                __half* __restrict__ qh, __half* __restrict__ kh, __half* __restrict__ vh){
  __shared__ __align__(16) _Float16 lA[128*64];   // 16 KB
  __shared__ __align__(16) _Float16 lB[128*64];   // 16 KB
  int nt = blockIdx.x;             // 0..11 : which = nt>>2, 128-col slab = nt&3
  int m0 = blockIdx.y * 128;
  int which = nt >> 2;
  int ncol0 = (nt & 3) * 128;
  int t = threadIdx.x;
  int w = t >> 6, lane = t & 63;
  int lrow = lane & 15, lk = lane >> 4;
  int wm = w >> 1, wn = w & 1;

  int rr = lane >> 3;
  int ss = (lane & 7) ^ rr;
  const __half* Abase = xh + (size_t)(m0 + w*32 + rr)*HIDDEN + ss*8;
  const __half* Bbase = whT + (size_t)which*ATTN*HIDDEN + (size_t)(ncol0 + w*32 + rr)*HIDDEN + ss*8;
  _Float16* lAw = &lA[(w*32)*64];
  _Float16* lBw = &lB[(w*32)*64];

  f32x4 acc[4][4];
  #pragma unroll
  for (int i=0;i<4;i++)
    #pragma unroll
    for (int j=0;j<4;j++) acc[i][j] = f32x4{0.f,0.f,0.f,0.f};

  for (int k0 = 0; k0 < HIDDEN; k0 += 64){
    __syncthreads();
    #pragma unroll
    for (int c=0; c<4; c++){
      gload16(Abase + (size_t)c*8*HIDDEN + k0, &lAw[c*8*64]);
      gload16(Bbase + (size_t)c*8*HIDDEN + k0, &lBw[c*8*64]);
    }
    __syncthreads();
    #pragma unroll
    for (int u=0; u<2; u++){
      f16x8 af[4], bf[4];
      #pragma unroll
      for (int fm=0; fm<4; fm++){
        int row = wm*64 + fm*16 + lrow;
        af[fm] = *(const f16x8*)&lA[row*64 + (((u*4 + lk) ^ (row & 7))*8)];
      }
      #pragma unroll
      for (int fn=0; fn<4; fn++){
        int row = wn*64 + fn*16 + lrow;
        bf[fn] = *(const f16x8*)&lB[row*64 + (((u*4 + lk) ^ (row & 7))*8)];
      }
      #pragma unroll
      for (int fm=0; fm<4; fm++)
        #pragma unroll
        for (int fn=0; fn<4; fn++)
          acc[fm][fn] = __builtin_amdgcn_mfma_f32_16x16x32_f16(af[fm], bf[fn], acc[fm][fn], 0,0,0);
    }
  }

  const float* bias = which==0 ? bq : (which==1 ? bk : bv);
  __half* dst = which==0 ? qh : (which==1 ? kh : vh);
  if (which < 2){
    int rt_base = (m0 >> 4) + wm*4;          // + fm
    int at_base = (ncol0 >> 5) + wn*2;       // + (fn>>1)
    #pragma unroll
    for (int fn=0; fn<4; fn++){
      int col = ncol0 + wn*64 + fn*16 + lrow;
      float bb = bias[col];
      int at = at_base + (fn >> 1);
      int asub = (fn & 1)*16 + lrow;
      #pragma unroll
      for (int fm=0; fm<4; fm++){
        size_t tbase = (size_t)(rt_base + fm)*8192 + (size_t)at*512 + asub;
        #pragma unroll
        for (int mi=0; mi<4; mi++)
          dst[tbase + (lk*4 + mi)*32] = __float2half(tanh_fast(acc[fm][fn][mi] + bb));
      }
    }
  } else {
    #pragma unroll
    for (int fn=0; fn<4; fn++){
      int col = ncol0 + wn*64 + fn*16 + lrow;
      float bb = bias[col];
      #pragma unroll
      for (int fm=0; fm<4; fm++)
        #pragma unroll
        for (int mi=0; mi<4; mi++){
          int row = m0 + wm*64 + fm*16 + lk*4 + mi;
          dst[(size_t)row*ATTN + col] = __float2half(tanh_fast(acc[fm][fn][mi] + bb));
        }
    }
  }
}

// ---------------- K1b: vh[16384][512] -> vT tiled [8][512/16][2048/32][16][32] ----------------
__global__ __launch_bounds__(256) void k_transpose_v(const __half* __restrict__ vh, __half* __restrict__ vT){
  __shared__ _Float16 lds[64][80];
  int r0 = blockIdx.x * 64;          // key rows
  int c0 = blockIdx.y * 64;          // attn cols
  int b = r0 / SEQ, j0 = r0 % SEQ;
  int t = threadIdx.x;
  #pragma unroll
  for (int it=0; it<2; it++){
    int g = it*256 + t;
    int r = g >> 3, s = g & 7;
    f16x8 v = *(const f16x8*)(vh + (size_t)(r0 + r)*ATTN + c0 + s*8);
    #pragma unroll
    for (int i=0;i<8;i++) lds[s*8+i][r] = v[i];
  }
  __syncthreads();
  __half* vb = vT + (size_t)b*ATTN*SEQ;
  #pragma unroll
  for (int it=0; it<2; it++){
    int g = it*256 + t;
    int ar = g >> 3, s = g & 7;
    f16x8 v = *(const f16x8*)&lds[ar][s*8];
    int a = c0 + ar;
    int j = j0 + s*8;
    *(f16x8*)(vb + (size_t)(a >> 4)*(16*SEQ) + (size_t)(j >> 5)*512 + (a & 15)*32 + (j & 31)) = v;
  }
}

// ---------------- K2: scores + no-max softmax ----------------
// Main path (p16 != null, probs == null): write ONLY tiled-fp16 P16 (67 MB).
// Fallback (probs != null, p16 == null): round-10 behavior, plain f32 probs stores.
__global__ __launch_bounds__(1024,4) void k_scores(const __half* __restrict__ qh, const __half* __restrict__ kh,
                                                   float* __restrict__ probs, __half* __restrict__ p16){
  __shared__ float red[16][32];
  int bid = blockIdx.x;
  int b  = bid & 7;            // XCD pin
  int i0 = (bid >> 3) * 32;
  int t = threadIdx.x;
  int w = t >> 6, lane = t & 63;
  int lrow = lane & 15, lk = lane >> 4;
  int loff = lrow*32 + lk*8;

  const __half* kbase = kh + (size_t)((b*SEQ + w*128) >> 4)*8192 + loff;  // +fn*8192 + it*512
  const __half* qbase = qh + (size_t)((b*SEQ + i0) >> 4)*8192 + loff;     // +nf*8192 + it*512

  f32x4 acc[2][8];
  #pragma unroll
  for (int i=0;i<2;i++)
    #pragma unroll
    for (int j=0;j<8;j++) acc[i][j] = f32x4{0.f,0.f,0.f,0.f};

  for (int it = 0; it < 16; it++){
    f16x8 aq0 = *(const f16x8*)(qbase + it*512);
    f16x8 aq1 = *(const f16x8*)(qbase + 8192 + it*512);
    #pragma unroll
    for (int fn=0; fn<8; fn++){
      f16x8 kf = *(const f16x8*)(kbase + (size_t)fn*8192 + it*512);
      acc[0][fn] = __builtin_amdgcn_mfma_f32_16x16x32_f16(kf, aq0, acc[0][fn], 0,0,0);
      acc[1][fn] = __builtin_amdgcn_mfma_f32_16x16x32_f16(kf, aq1, acc[1][fn], 0,0,0);
    }
  }

  // no-max softmax: |s*scale| <= 22.63, f32-safe (verified rounds 7-12)
  const float scale = 0.044194173824159216f;   // 1/sqrt(512)
  float sm[2];
  #pragma unroll
  for (int nf=0;nf<2;nf++){
    float s = 0.f;
    #pragma unroll
    for (int fn=0;fn<8;fn++)
      #pragma unroll
      for (int mi=0;mi<4;mi++){
        float e = __expf(acc[nf][fn][mi] * scale);
        acc[nf][fn][mi] = e;
        s += e;
      }
    s += __shfl_xor(s, 16);
    s += __shfl_xor(s, 32);
    sm[nf] = s;
  }
  if (lane < 16){ red[w][lane] = sm[0]; red[w][16 + lane] = sm[1]; }
  __syncthreads();
  float inv[2];
  #pragma unroll
  for (int nf=0;nf<2;nf++){
    float tot = 0.f;
    #pragma unroll
    for (int ww=0; ww<16; ww++) tot += red[ww][nf*16 + lrow];
    inv[nf] = 1.0f / tot;
  }
  #pragma unroll
  for (int nf=0;nf<2;nf++){
    f32x4 iv = {inv[nf], inv[nf], inv[nf], inv[nf]};
    size_t tq = (size_t)((i0 >> 4) + nf);
    #pragma unroll
    for (int fn=0;fn<8;fn++){
      f32x4 v = acc[nf][fn] * iv;
      if (probs){
        size_t rowoff = (size_t)(i0 + nf*16 + lrow)*SEQ + w*128 + lk*4;
        *(f32x4*)(probs + (size_t)b*SEQ*SEQ + rowoff + fn*16) = v;
      }
      if (p16){
        f16x4 h;
        h[0]=(_Float16)v[0]; h[1]=(_Float16)v[1]; h[2]=(_Float16)v[2]; h[3]=(_Float16)v[3];
        *(f16x4*)&p16[(size_t)b*SEQ*SEQ + tq*32768 + (size_t)(w*4 + (fn>>1))*512 + lrow*32 + (fn&1)*16 + lk*4] = h;
      }
    }
  }
}

// ---------------- K3main: context + probs expansion, 64 q-rows/block ----------------
// 256 blocks (1/CU), 512 thr (8 waves). Block: 64 q-rows x 512 cols; wave w: cols [w*64, +64).
// acc[4][4]=64 f32 + ~55 VGPR fits the 128-reg/wave cap at 4 waves/SIMD.
// Halved block count => halved redundant vT L2 traffic vs the 32-row version.
// Wave w also expands P16 -> f32 probs (NT) for key-tiles kt in [w*8, w*8+8), all 4 nf.
__global__ __launch_bounds__(512,4) void k_pv_p16(const __half* __restrict__ p16, const __half* __restrict__ vT,
                                                  float* __restrict__ probs, float* __restrict__ out0){
  int bid = blockIdx.x;
  int b  = bid & 7;            // XCD pin
  int i0 = (bid >> 3) * 64;
  int t = threadIdx.x;
  int w = t >> 6, lane = t & 63;
  int lrow = lane & 15, lk = lane >> 4;
  int loff = lrow*32 + lk*8;

  const __half* pbase = p16 + (size_t)b*SEQ*SEQ + (size_t)(i0 >> 4)*32768 + loff;   // + nf*32768 + kt*512
  const __half* vbase = vT + (size_t)b*ATTN*SEQ + (size_t)(w*4)*32768 + loff;        // + cf*32768 + kt*512
  float* prow = probs + ((size_t)b*SEQ + i0 + lrow)*SEQ + lk*8;                      // + nf*16*SEQ + kt*32

  f32x4 acc[4][4];
  #pragma unroll
  for (int i=0;i<4;i++)
    #pragma unroll
    for (int j=0;j<4;j++) acc[i][j] = f32x4{0.f,0.f,0.f,0.f};

  for (int kt = 0; kt < 64; kt++){
    f16x8 pa[4];
    #pragma unroll
    for (int nf=0; nf<4; nf++)
      pa[nf] = *(const f16x8*)(pbase + (size_t)nf*32768 + kt*512);
    if ((kt >> 3) == w){   // this wave expands these key-tiles to f32 probs
      #pragma unroll
      for (int nf=0; nf<4; nf++){
        f32x4 lo = {(float)pa[nf][0], (float)pa[nf][1], (float)pa[nf][2], (float)pa[nf][3]};
        f32x4 hi = {(float)pa[nf][4], (float)pa[nf][5], (float)pa[nf][6], (float)pa[nf][7]};
        float* pr = prow + (size_t)nf*16*SEQ + kt*32;
        __builtin_nontemporal_store(lo, (f32x4*)(pr));
        __builtin_nontemporal_store(hi, (f32x4*)(pr + 4));
      }
    }
    #pragma unroll
    for (int cf=0; cf<4; cf++){
      f16x8 bv8 = *(const f16x8*)(vbase + (size_t)cf*32768 + kt*512);
      #pragma unroll
      for (int nf=0; nf<4; nf++)
        acc[nf][cf] = __builtin_amdgcn_mfma_f32_16x16x32_f16(pa[nf], bv8, acc[nf][cf], 0,0,0);
    }
  }

  float* dst = out0 + ((size_t)b*SEQ + i0)*ATTN + w*64;
  #pragma unroll
  for (int nf=0; nf<4; nf++)
    #pragma unroll
    for (int cf=0; cf<4; cf++)
      #pragma unroll
      for (int mi=0; mi<4; mi++)
        dst[(size_t)(nf*16 + lk*4 + mi)*ATTN + cf*16 + lrow] = tanh_fast(acc[nf][cf][mi]);
}

// ---------------- K3 fallback: context = probs(f32) @ v — round-10 version ----------------
__global__ __launch_bounds__(512,4) void k_pv(const float* __restrict__ probs, const __half* __restrict__ vT,
                                              float* __restrict__ out0){
  int bid = blockIdx.x;
  int b  = bid & 7;
  int i0 = (bid >> 3) * 32;
  int t = threadIdx.x;
  int w = t >> 6, lane = t & 63;
  int lrow = lane & 15, lk = lane >> 4;
  int loff = lrow*32 + lk*8;

  const float* pbase = probs + ((size_t)b*SEQ + i0 + lrow)*SEQ + lk*8;
  const __half* vbase = vT + (size_t)b*ATTN*SEQ + (size_t)(w*4)*32768 + loff;

  f32x4 acc[2][4];
  #pragma unroll
  for (int i=0;i<2;i++)
    #pragma unroll
    for (int j=0;j<4;j++) acc[i][j] = f32x4{0.f,0.f,0.f,0.f};

  for (int kt = 0; kt < 64; kt++){
    int k0 = kt*32;
    f16x8 af[2];
    #pragma unroll
    for (int nf=0; nf<2; nf++){
      const float* pr = pbase + (size_t)nf*16*SEQ + k0;
      float4 a = *(const float4*)(pr);
      float4 c = *(const float4*)(pr + 4);
      f16x8 h;
      h[0]=(_Float16)a.x; h[1]=(_Float16)a.y; h[2]=(_Float16)a.z; h[3]=(_Float16)a.w;
      h[4]=(_Float16)c.x; h[5]=(_Float16)c.y; h[6]=(_Float16)c.z; h[7]=(_Float16)c.w;
      af[nf] = h;
    }
    #pragma unroll
    for (int cf=0; cf<4; cf++){
      f16x8 bv8 = *(const f16x8*)(vbase + (size_t)cf*32768 + kt*512);
      acc[0][cf] = __builtin_amdgcn_mfma_f32_16x16x32_f16(af[0], bv8, acc[0][cf], 0,0,0);
      acc[1][cf] = __builtin_amdgcn_mfma_f32_16x16x32_f16(af[1], bv8, acc[1][cf], 0,0,0);
    }
  }

  float* dst = out0 + ((size_t)b*SEQ + i0)*ATTN + w*64;
  #pragma unroll
  for (int nf=0; nf<2; nf++)
    #pragma unroll
    for (int cf=0; cf<4; cf++)
      #pragma unroll
      for (int mi=0; mi<4; mi++)
        dst[(size_t)(nf*16 + lk*4 + mi)*ATTN + cf*16 + lrow] = tanh_fast(acc[nf][cf][mi]);
}

extern "C" void kernel_launch(void* const* d_in, const int* in_sizes, int n_in,
                              void* d_out, int out_size, void* d_ws, size_t ws_size,
                              hipStream_t stream){
  const float* x  = (const float*)d_in[0];
  const float* Wq = (const float*)d_in[1];
  const float* bq = (const float*)d_in[2];
  const float* Wk = (const float*)d_in[3];
  const float* bk = (const float*)d_in[4];
  const float* Wv = (const float*)d_in[5];
  const float* bv = (const float*)d_in[6];

  float* out0 = (float*)d_out;                        // [8,2048,512]  tanh(context)   33.55 MB
  float* out1 = out0 + (size_t)NB*SEQ*ATTN;           // [8,2048,2048] probs          134.2 MB

  const size_t SZ = 16777216;                         // 16.78 MB
  char* ws = (char*)d_ws;

  if (ws_size >= 5*SZ){
    // MAIN path. ws: vT | p16. out1 scratch: xh | whT | vh | qh | kh (all dead
    // before k_pv_p16 overwrites out1 with probs). out0 written ONCE, by the
    // final kernel. No output doubles as scratch for itself.
    __half* vT  = (__half*)ws;                           // 16.78 MB tiled
    __half* p16 = (__half*)(ws + SZ);                    // 67.1 MB tiled
    __half* xh  = (__half*)out1;                         // 33.55 MB
    __half* whT = (__half*)((char*)out1 + 2*SZ);         // 3.15 MB
    __half* vh  = (__half*)((char*)out1 + 2*SZ + 3145728);          // 16.78 MB
    __half* qh  = (__half*)((char*)out1 + 3*SZ + 3145728);          // 16.78 MB tiled
    __half* kh  = (__half*)((char*)out1 + 4*SZ + 3145728);          // 16.78 MB tiled -> ends 87 MB < 134 MB
    k_cast_x     <<<8192,        256, 0, stream>>>(x, xh);
    k_transpose_w<<<dim3(512,3), 256, 0, stream>>>(Wq, Wk, Wv, whT);
    k_proj       <<<dim3(12,128),256, 0, stream>>>(xh, whT, bq, bk, bv, qh, kh, vh);
    k_transpose_v<<<dim3(256,8), 256, 0, stream>>>(vh, vT);
    k_scores     <<<512,        1024, 0, stream>>>(qh, kh, (float*)nullptr, p16);
    k_pv_p16     <<<256,         512, 0, stream>>>(p16, vT, out1, out0);
  } else if (ws_size >= 3*SZ){
    // round-10 fallback: qh/kh in ws, f32-probs-reading k_pv  (passed @389 us)
    __half* vT = (__half*)ws;
    __half* qh = (__half*)(ws + SZ);
    __half* kh = (__half*)(ws + 2*SZ);
    __half* xh  = (__half*)out1;
    __half* whT = (__half*)((char*)out1 + 2*SZ);
    __half* vh  = (__half*)((char*)out1 + 2*SZ + 3145728);
    k_cast_x     <<<8192,        256, 0, stream>>>(x, xh);
    k_transpose_w<<<dim3(512,3), 256, 0, stream>>>(Wq, Wk, Wv, whT);
    k_proj       <<<dim3(12,128),256, 0, stream>>>(xh, whT, bq, bk, bv, qh, kh, vh);
    k_transpose_v<<<dim3(256,8), 256, 0, stream>>>(vh, vT);
    k_scores     <<<512,        1024, 0, stream>>>(qh, kh, out1, ((__half*)nullptr));
    k_pv         <<<512,         512, 0, stream>>>(out1, vT, out0);
  } else {
    // minimal-ws fallback: qh/kh overlay out0
    __half* vT = (__half*)ws;
    __half* qh = (__half*)out0;
    __half* kh = (__half*)out0 + (size_t)MROWS*ATTN;
    __half* xh  = (__half*)out1;
    __half* whT = (__half*)((char*)out1 + 2*SZ);
    __half* vh  = (__half*)((char*)out1 + 2*SZ + 3145728);
    k_cast_x     <<<8192,        256, 0, stream>>>(x, xh);
    k_transpose_w<<<dim3(512,3), 256, 0, stream>>>(Wq, Wk, Wv, whT);
    k_proj       <<<dim3(12,128),256, 0, stream>>>(xh, whT, bq, bk, bv, qh, kh, vh);
    k_transpose_v<<<dim3(256,8), 256, 0, stream>>>(vh, vT);
    k_scores     <<<512,        1024, 0, stream>>>(qh, kh, out1, ((__half*)nullptr));
    k_pv         <<<512,         512, 0, stream>>>(out1, vT, out0);
  }
}

// Round 14
// 278.072 us; speedup vs baseline: 1.7229x; 1.0369x over previous
//
#include <hip/hip_runtime.h>
#include <hip/hip_fp16.h>
#include <cstdint>

#define HIDDEN 1024
#define ATTN   512
#define NB     8
#define SEQ    2048
#define MROWS  (NB*SEQ)   // 16384

typedef _Float16 f16x8 __attribute__((ext_vector_type(8)));
typedef _Float16 f16x4 __attribute__((ext_vector_type(4)));
typedef float    f32x4 __attribute__((ext_vector_type(4)));

// Fragment-major tiled layout for all fp16 MFMA operands (q/k/vT/P16):
//   addr(r, c) = (r>>4)*(16*C) + (c>>5)*512 + (r&15)*32 + (c&31)   [halfs]
// => a wave's 16x32 fragment is one contiguous 1KB block (single-segment load).

__device__ __forceinline__ float tanh_fast(float x){
  float e = __expf(2.0f*x);
  return 1.0f - 2.0f/(e + 1.0f);
}

__device__ __forceinline__ void gload16(const void* g, void* l){
  __builtin_amdgcn_global_load_lds((const __attribute__((address_space(1))) void*)g,
                                   (__attribute__((address_space(3))) void*)l, 16, 0, 0);
}

// ---------------- K0a: cast inputs f32 -> fp16 ----------------
__global__ __launch_bounds__(256) void k_cast_x(const float* __restrict__ x, __half* __restrict__ xh){
  size_t i = (size_t)blockIdx.x*256 + threadIdx.x;
  const float4* src = reinterpret_cast<const float4*>(x) + i*2;
  float4 a = src[0], b = src[1];
  f16x8 h;
  h[0]=(_Float16)a.x; h[1]=(_Float16)a.y; h[2]=(_Float16)a.z; h[3]=(_Float16)a.w;
  h[4]=(_Float16)b.x; h[5]=(_Float16)b.y; h[6]=(_Float16)b.z; h[7]=(_Float16)b.w;
  reinterpret_cast<f16x8*>(xh)[i] = h;
}

// ---------------- K0b: W[1024][512] f32 -> WhT[512][1024] fp16 (x3) ----------------
__global__ __launch_bounds__(256) void k_transpose_w(const float* __restrict__ Wq, const float* __restrict__ Wk,
                                                     const float* __restrict__ Wv, __half* __restrict__ whT){
  __shared__ float lds[32][33];
  int which = blockIdx.y;
  const float* W = which==0 ? Wq : (which==1 ? Wk : Wv);
  int tr = blockIdx.x >> 4;
  int tc = blockIdx.x & 15;
  int t = threadIdx.x;
  {
    int r = t >> 3, c4 = (t & 7)*4;
    float4 v = *reinterpret_cast<const float4*>(W + (size_t)(tr*32 + r)*ATTN + tc*32 + c4);
    lds[r][c4+0]=v.x; lds[r][c4+1]=v.y; lds[r][c4+2]=v.z; lds[r][c4+3]=v.w;
  }
  __syncthreads();
  {
    int n = t >> 3, k4 = (t & 7)*4;
    ushort4 u;
    u.x = __half_as_ushort(__float2half(lds[k4+0][n]));
    u.y = __half_as_ushort(__float2half(lds[k4+1][n]));
    u.z = __half_as_ushort(__float2half(lds[k4+2][n]));
    u.w = __half_as_ushort(__float2half(lds[k4+3][n]));
    *reinterpret_cast<ushort4*>(whT + (size_t)which*ATTN*HIDDEN + (size_t)(tc*32 + n)*HIDDEN + tr*32 + k4) = u;
  }
}

// ---------------- K1: fused QKV projection ----------------
// q/k outputs fragment-tiled; v written DIRECTLY in vT-tiled layout (k_transpose_v deleted).
__global__ __launch_bounds__(256,3) void k_proj(const __half* __restrict__ xh, const __half* __restrict__ whT,
                                                const float* __restrict__ bq, const float* __restrict__ bk,
                                                const float* __restrict__ bv,
                                                __half* __restrict__ qh, __half* __restrict__ kh, __half* __restrict__ vT){
  __shared__ __align__(16) _Float16 lA[128*64];   // 16 KB
  __shared__ __align__(16) _Float16 lB[128*64];   // 16 KB
  int nt = blockIdx.x;             // 0..11 : which = nt>>2, 128-col slab = nt&3
  int m0 = blockIdx.y * 128;
  int which = nt >> 2;
  int ncol0 = (nt & 3) * 128;
  int t = threadIdx.x;
  int w = t >> 6, lane = t & 63;
  int lrow = lane & 15, lk = lane >> 4;
  int wm = w >> 1, wn = w & 1;

  int rr = lane >> 3;
  int ss = (lane & 7) ^ rr;
  const __half* Abase = xh + (size_t)(m0 + w*32 + rr)*HIDDEN + ss*8;
  const __half* Bbase = whT + (size_t)which*ATTN*HIDDEN + (size_t)(ncol0 + w*32 + rr)*HIDDEN + ss*8;
  _Float16* lAw = &lA[(w*32)*64];
  _Float16* lBw = &lB[(w*32)*64];

  f32x4 acc[4][4];
  #pragma unroll
  for (int i=0;i<4;i++)
    #pragma unroll
    for (int j=0;j<4;j++) acc[i][j] = f32x4{0.f,0.f,0.f,0.f};

  for (int k0 = 0; k0 < HIDDEN; k0 += 64){
    __syncthreads();
    #pragma unroll
    for (int c=0; c<4; c++){
      gload16(Abase + (size_t)c*8*HIDDEN + k0, &lAw[c*8*64]);
      gload16(Bbase + (size_t)c*8*HIDDEN + k0, &lBw[c*8*64]);
    }
    __syncthreads();
    #pragma unroll
    for (int u=0; u<2; u++){
      f16x8 af[4], bf[4];
      #pragma unroll
      for (int fm=0; fm<4; fm++){
        int row = wm*64 + fm*16 + lrow;
        af[fm] = *(const f16x8*)&lA[row*64 + (((u*4 + lk) ^ (row & 7))*8)];
      }
      #pragma unroll
      for (int fn=0; fn<4; fn++){
        int row = wn*64 + fn*16 + lrow;
        bf[fn] = *(const f16x8*)&lB[row*64 + (((u*4 + lk) ^ (row & 7))*8)];
      }
      #pragma unroll
      for (int fm=0; fm<4; fm++)
        #pragma unroll
        for (int fn=0; fn<4; fn++)
          acc[fm][fn] = __builtin_amdgcn_mfma_f32_16x16x32_f16(af[fm], bf[fn], acc[fm][fn], 0,0,0);
    }
  }

  const float* bias = which==0 ? bq : (which==1 ? bk : bv);
  if (which < 2){
    __half* dst = which==0 ? qh : kh;
    int rt_base = (m0 >> 4) + wm*4;          // + fm
    int at_base = (ncol0 >> 5) + wn*2;       // + (fn>>1)
    #pragma unroll
    for (int fn=0; fn<4; fn++){
      int col = ncol0 + wn*64 + fn*16 + lrow;
      float bb = bias[col];
      int at = at_base + (fn >> 1);
      int asub = (fn & 1)*16 + lrow;
      #pragma unroll
      for (int fm=0; fm<4; fm++){
        size_t tbase = (size_t)(rt_base + fm)*8192 + (size_t)at*512 + asub;
        #pragma unroll
        for (int mi=0; mi<4; mi++)
          dst[tbase + (lk*4 + mi)*32] = __float2half(tanh_fast(acc[fm][fn][mi] + bb));
      }
    }
  } else {
    // v: direct vT-tiled store. a = attn col, j = key row (within batch).
    //   addr = (a>>4)*32768 + (j>>5)*512 + (a&15)*32 + (j&31); mi lands on
    //   consecutive halfs -> f16x4 vector store per (fn,fm).
    __half* vb = vT + (size_t)(m0 >> 11)*ATTN*SEQ;   // batch = m0/2048
    int jb0 = (m0 & 2047) + wm*64;                   // + fm*16
    int at0 = (ncol0 >> 4) + wn*4;                   // + fn
    #pragma unroll
    for (int fn=0; fn<4; fn++){
      int col = ncol0 + wn*64 + fn*16 + lrow;
      float bb = bias[col];
      #pragma unroll
      for (int fm=0; fm<4; fm++){
        int jb = jb0 + fm*16;
        f16x4 h;
        #pragma unroll
        for (int mi=0; mi<4; mi++) h[mi] = (_Float16)tanh_fast(acc[fm][fn][mi] + bb);
        *(f16x4*)(vb + (size_t)(at0 + fn)*32768 + (size_t)(jb >> 5)*512 + lrow*32 + (jb & 16) + lk*4) = h;
      }
    }
  }
}

// ---------------- K2: scores + no-max softmax ----------------
// Main path (p16 != null, probs == null): write ONLY tiled-fp16 P16 (67 MB).
// Fallback (probs != null, p16 == null): plain f32 probs stores.
__global__ __launch_bounds__(1024,4) void k_scores(const __half* __restrict__ qh, const __half* __restrict__ kh,
                                                   float* __restrict__ probs, __half* __restrict__ p16){
  __shared__ float red[16][32];
  int bid = blockIdx.x;
  int b  = bid & 7;            // XCD pin
  int i0 = (bid >> 3) * 32;
  int t = threadIdx.x;
  int w = t >> 6, lane = t & 63;
  int lrow = lane & 15, lk = lane >> 4;
  int loff = lrow*32 + lk*8;

  const __half* kbase = kh + (size_t)((b*SEQ + w*128) >> 4)*8192 + loff;  // +fn*8192 + it*512
  const __half* qbase = qh + (size_t)((b*SEQ + i0) >> 4)*8192 + loff;     // +nf*8192 + it*512

  f32x4 acc[2][8];
  #pragma unroll
  for (int i=0;i<2;i++)
    #pragma unroll
    for (int j=0;j<8;j++) acc[i][j] = f32x4{0.f,0.f,0.f,0.f};

  for (int it = 0; it < 16; it++){
    f16x8 aq0 = *(const f16x8*)(qbase + it*512);
    f16x8 aq1 = *(const f16x8*)(qbase + 8192 + it*512);
    #pragma unroll
    for (int fn=0; fn<8; fn++){
      f16x8 kf = *(const f16x8*)(kbase + (size_t)fn*8192 + it*512);
      acc[0][fn] = __builtin_amdgcn_mfma_f32_16x16x32_f16(kf, aq0, acc[0][fn], 0,0,0);
      acc[1][fn] = __builtin_amdgcn_mfma_f32_16x16x32_f16(kf, aq1, acc[1][fn], 0,0,0);
    }
  }

  // no-max softmax: |s*scale| <= 22.63, f32-safe (verified rounds 7-13)
  const float scale = 0.044194173824159216f;   // 1/sqrt(512)
  float sm[2];
  #pragma unroll
  for (int nf=0;nf<2;nf++){
    float s = 0.f;
    #pragma unroll
    for (int fn=0;fn<8;fn++)
      #pragma unroll
      for (int mi=0;mi<4;mi++){
        float e = __expf(acc[nf][fn][mi] * scale);
        acc[nf][fn][mi] = e;
        s += e;
      }
    s += __shfl_xor(s, 16);
    s += __shfl_xor(s, 32);
    sm[nf] = s;
  }
  if (lane < 16){ red[w][lane] = sm[0]; red[w][16 + lane] = sm[1]; }
  __syncthreads();
  float inv[2];
  #pragma unroll
  for (int nf=0;nf<2;nf++){
    float tot = 0.f;
    #pragma unroll
    for (int ww=0; ww<16; ww++) tot += red[ww][nf*16 + lrow];
    inv[nf] = 1.0f / tot;
  }
  #pragma unroll
  for (int nf=0;nf<2;nf++){
    f32x4 iv = {inv[nf], inv[nf], inv[nf], inv[nf]};
    size_t tq = (size_t)((i0 >> 4) + nf);
    #pragma unroll
    for (int fn=0;fn<8;fn++){
      f32x4 v = acc[nf][fn] * iv;
      if (probs){
        size_t rowoff = (size_t)(i0 + nf*16 + lrow)*SEQ + w*128 + lk*4;
        *(f32x4*)(probs + (size_t)b*SEQ*SEQ + rowoff + fn*16) = v;
      }
      if (p16){
        f16x4 h;
        h[0]=(_Float16)v[0]; h[1]=(_Float16)v[1]; h[2]=(_Float16)v[2]; h[3]=(_Float16)v[3];
        *(f16x4*)&p16[(size_t)b*SEQ*SEQ + tq*32768 + (size_t)(w*4 + (fn>>1))*512 + lrow*32 + (fn&1)*16 + lk*4] = h;
      }
    }
  }
}

// ---------------- K3main: context + probs expansion, 64 q-rows/block ----------------
// 256 blocks (1/CU), 512 thr (8 waves). Block: 64 q-rows x 512 cols; wave w: cols [w*64, +64).
// All loads are contiguous 1KB fragments; out0 stores nontemporal (never re-read).
__global__ __launch_bounds__(512,4) void k_pv_p16(const __half* __restrict__ p16, const __half* __restrict__ vT,
                                                  float* __restrict__ probs, float* __restrict__ out0){
  int bid = blockIdx.x;
  int b  = bid & 7;            // XCD pin
  int i0 = (bid >> 3) * 64;
  int t = threadIdx.x;
  int w = t >> 6, lane = t & 63;
  int lrow = lane & 15, lk = lane >> 4;
  int loff = lrow*32 + lk*8;

  const __half* pbase = p16 + (size_t)b*SEQ*SEQ + (size_t)(i0 >> 4)*32768 + loff;   // + nf*32768 + kt*512
  const __half* vbase = vT + (size_t)b*ATTN*SEQ + (size_t)(w*4)*32768 + loff;        // + cf*32768 + kt*512
  float* prow = probs + ((size_t)b*SEQ + i0 + lrow)*SEQ + lk*8;                      // + nf*16*SEQ + kt*32

  f32x4 acc[4][4];
  #pragma unroll
  for (int i=0;i<4;i++)
    #pragma unroll
    for (int j=0;j<4;j++) acc[i][j] = f32x4{0.f,0.f,0.f,0.f};

  for (int kt = 0; kt < 64; kt++){
    f16x8 pa[4];
    #pragma unroll
    for (int nf=0; nf<4; nf++)
      pa[nf] = *(const f16x8*)(pbase + (size_t)nf*32768 + kt*512);
    if ((kt >> 3) == w){   // this wave expands these key-tiles to f32 probs
      #pragma unroll
      for (int nf=0; nf<4; nf++){
        f32x4 lo = {(float)pa[nf][0], (float)pa[nf][1], (float)pa[nf][2], (float)pa[nf][3]};
        f32x4 hi = {(float)pa[nf][4], (float)pa[nf][5], (float)pa[nf][6], (float)pa[nf][7]};
        float* pr = prow + (size_t)nf*16*SEQ + kt*32;
        __builtin_nontemporal_store(lo, (f32x4*)(pr));
        __builtin_nontemporal_store(hi, (f32x4*)(pr + 4));
      }
    }
    #pragma unroll
    for (int cf=0; cf<4; cf++){
      f16x8 bv8 = *(const f16x8*)(vbase + (size_t)cf*32768 + kt*512);
      #pragma unroll
      for (int nf=0; nf<4; nf++)
        acc[nf][cf] = __builtin_amdgcn_mfma_f32_16x16x32_f16(pa[nf], bv8, acc[nf][cf], 0,0,0);
    }
  }

  float* dst = out0 + ((size_t)b*SEQ + i0)*ATTN + w*64;
  #pragma unroll
  for (int nf=0; nf<4; nf++)
    #pragma unroll
    for (int cf=0; cf<4; cf++)
      #pragma unroll
      for (int mi=0; mi<4; mi++)
        __builtin_nontemporal_store(tanh_fast(acc[nf][cf][mi]),
                                    dst + (size_t)(nf*16 + lk*4 + mi)*ATTN + cf*16 + lrow);
}

// ---------------- K3 fallback: context = probs(f32) @ v ----------------
__global__ __launch_bounds__(512,4) void k_pv(const float* __restrict__ probs, const __half* __restrict__ vT,
                                              float* __restrict__ out0){
  int bid = blockIdx.x;
  int b  = bid & 7;
  int i0 = (bid >> 3) * 32;
  int t = threadIdx.x;
  int w = t >> 6, lane = t & 63;
  int lrow = lane & 15, lk = lane >> 4;
  int loff = lrow*32 + lk*8;

  const float* pbase = probs + ((size_t)b*SEQ + i0 + lrow)*SEQ + lk*8;
  const __half* vbase = vT + (size_t)b*ATTN*SEQ + (size_t)(w*4)*32768 + loff;

  f32x4 acc[2][4];
  #pragma unroll
  for (int i=0;i<2;i++)
    #pragma unroll
    for (int j=0;j<4;j++) acc[i][j] = f32x4{0.f,0.f,0.f,0.f};

  for (int kt = 0; kt < 64; kt++){
    int k0 = kt*32;
    f16x8 af[2];
    #pragma unroll
    for (int nf=0; nf<2; nf++){
      const float* pr = pbase + (size_t)nf*16*SEQ + k0;
      float4 a = *(const float4*)(pr);
      float4 c = *(const float4*)(pr + 4);
      f16x8 h;
      h[0]=(_Float16)a.x; h[1]=(_Float16)a.y; h[2]=(_Float16)a.z; h[3]=(_Float16)a.w;
      h[4]=(_Float16)c.x; h[5]=(_Float16)c.y; h[6]=(_Float16)c.z; h[7]=(_Float16)c.w;
      af[nf] = h;
    }
    #pragma unroll
    for (int cf=0; cf<4; cf++){
      f16x8 bv8 = *(const f16x8*)(vbase + (size_t)cf*32768 + kt*512);
      acc[0][cf] = __builtin_amdgcn_mfma_f32_16x16x32_f16(af[0], bv8, acc[0][cf], 0,0,0);
      acc[1][cf] = __builtin_amdgcn_mfma_f32_16x16x32_f16(af[1], bv8, acc[1][cf], 0,0,0);
    }
  }

  float* dst = out0 + ((size_t)b*SEQ + i0)*ATTN + w*64;
  #pragma unroll
  for (int nf=0; nf<2; nf++)
    #pragma unroll
    for (int cf=0; cf<4; cf++)
      #pragma unroll
      for (int mi=0; mi<4; mi++)
        dst[(size_t)(nf*16 + lk*4 + mi)*ATTN + cf*16 + lrow] = tanh_fast(acc[nf][cf][mi]);
}

extern "C" void kernel_launch(void* const* d_in, const int* in_sizes, int n_in,
                              void* d_out, int out_size, void* d_ws, size_t ws_size,
                              hipStream_t stream){
  const float* x  = (const float*)d_in[0];
  const float* Wq = (const float*)d_in[1];
  const float* bq = (const float*)d_in[2];
  const float* Wk = (const float*)d_in[3];
  const float* bk = (const float*)d_in[4];
  const float* Wv = (const float*)d_in[5];
  const float* bv = (const float*)d_in[6];

  float* out0 = (float*)d_out;                        // [8,2048,512]  tanh(context)   33.55 MB
  float* out1 = out0 + (size_t)NB*SEQ*ATTN;           // [8,2048,2048] probs          134.2 MB

  const size_t SZ = 16777216;                         // 16.78 MB
  char* ws = (char*)d_ws;

  if (ws_size >= 5*SZ){
    // MAIN path. ws: vT | p16. out1 scratch: xh | whT | qh | kh (all dead
    // before k_pv_p16 overwrites out1 with probs). out0 written ONCE, by the
    // final kernel.
    __half* vT  = (__half*)ws;                           // 16.78 MB tiled (written by k_proj)
    __half* p16 = (__half*)(ws + SZ);                    // 67.1 MB tiled
    __half* xh  = (__half*)out1;                         // 33.55 MB
    __half* whT = (__half*)((char*)out1 + 2*SZ);         // 3.15 MB
    __half* qh  = (__half*)((char*)out1 + 2*SZ + 3145728);          // 16.78 MB tiled
    __half* kh  = (__half*)((char*)out1 + 3*SZ + 3145728);          // 16.78 MB tiled -> ends ~70 MB < 134 MB
    k_cast_x     <<<8192,        256, 0, stream>>>(x, xh);
    k_transpose_w<<<dim3(512,3), 256, 0, stream>>>(Wq, Wk, Wv, whT);
    k_proj       <<<dim3(12,128),256, 0, stream>>>(xh, whT, bq, bk, bv, qh, kh, vT);
    k_scores     <<<512,        1024, 0, stream>>>(qh, kh, (float*)nullptr, p16);
    k_pv_p16     <<<256,         512, 0, stream>>>(p16, vT, out1, out0);
  } else if (ws_size >= 3*SZ){
    // fallback: qh/kh in ws, f32-probs-reading k_pv
    __half* vT = (__half*)ws;
    __half* qh = (__half*)(ws + SZ);
    __half* kh = (__half*)(ws + 2*SZ);
    __half* xh  = (__half*)out1;
    __half* whT = (__half*)((char*)out1 + 2*SZ);
    k_cast_x     <<<8192,        256, 0, stream>>>(x, xh);
    k_transpose_w<<<dim3(512,3), 256, 0, stream>>>(Wq, Wk, Wv, whT);
    k_proj       <<<dim3(12,128),256, 0, stream>>>(xh, whT, bq, bk, bv, qh, kh, vT);
    k_scores     <<<512,        1024, 0, stream>>>(qh, kh, out1, ((__half*)nullptr));
    k_pv         <<<512,         512, 0, stream>>>(out1, vT, out0);
  } else {
    // minimal-ws fallback: qh/kh overlay out0
    __half* vT = (__half*)ws;
    __half* qh = (__half*)out0;
    __half* kh = (__half*)out0 + (size_t)MROWS*ATTN;
    __half* xh  = (__half*)out1;
    __half* whT = (__half*)((char*)out1 + 2*SZ);
    k_cast_x     <<<8192,        256, 0, stream>>>(x, xh);
    k_transpose_w<<<dim3(512,3), 256, 0, stream>>>(Wq, Wk, Wv, whT);
    k_proj       <<<dim3(12,128),256, 0, stream>>>(xh, whT, bq, bk, bv, qh, kh, vT);
    k_scores     <<<512,        1024, 0, stream>>>(qh, kh, out1, ((__half*)nullptr));
    k_pv         <<<512,         512, 0, stream>>>(out1, vT, out0);
  }
}